// Round 11
// baseline (144.728 us; speedup 1.0000x reference)
//
#include <hip/hip_runtime.h>
#include <hip/hip_bf16.h>
#include <math.h>

#define P_N   2048
#define B_N   10000
#define NB    15
#define MROWS (P_N * NB)   // 30720
#define SPLIT 5
#define BPB   (B_N / SPLIT)  // 2000 boundary points per scan block

typedef __bf16 bf16x8 __attribute__((ext_vector_type(8)));
typedef float  f32x4  __attribute__((ext_vector_type(4)));

__device__ __forceinline__ float bf2f(unsigned short u) {
    union { unsigned int i; float f; } v; v.i = ((unsigned int)u) << 16; return v.f;
}
__device__ __forceinline__ unsigned short f2bf(float f) {
    union { float f; unsigned int i; } v; v.f = f;
    unsigned int i = v.i;
    i += 0x7FFFu + ((i >> 16) & 1u);
    return (unsigned short)(i >> 16);
}
__device__ __forceinline__ void gld_lds16(const unsigned short* g, unsigned short* l) {
    __builtin_amdgcn_global_load_lds(
        (const __attribute__((address_space(1))) unsigned int*)g,
        (__attribute__((address_space(3))) unsigned int*)l, 16, 0, 0);
}
// monotone u32 key for f32 (x<y iff key(x)<key(y)); all real keys > 0
__device__ __forceinline__ unsigned fkey(float f) {
    unsigned b = __float_as_uint(f);
    return (b & 0x80000000u) ? ~b : (b | 0x80000000u);
}
__device__ __forceinline__ float funkey(unsigned key) {
    unsigned b = (key & 0x80000000u) ? (key ^ 0x80000000u) : ~key;
    return __uint_as_float(b);
}

// ---- K0: tiled transpose W1/W2 -> bf16 [N][K]; zero stats/keys/maxkeys ------
__global__ __launch_bounds__(256) void k_prep(const float* __restrict__ W1,
        const float* __restrict__ W2, unsigned short* __restrict__ w1t,
        unsigned short* __restrict__ w2t, float* __restrict__ stats,
        unsigned long long* __restrict__ keys, unsigned int* __restrict__ mkey) {
    int blk = blockIdx.x, tid = threadIdx.x;
    if (blk < 144) {
        __shared__ unsigned short t[64][65];
        const float* W; unsigned short* O; int NC, K, tr, tc;
        if (blk < 16) { W = W1; O = w1t; NC = 512; K = 128; tr = blk & 1; tc = blk >> 1; }
        else { int b = blk - 16; W = W2; O = w2t; NC = 1024; K = 512; tr = b & 7; tc = b >> 3; }
        int r0 = tr * 64, c0 = tc * 64;
        int cx = tid & 63, rg = tid >> 6;
#pragma unroll
        for (int i = 0; i < 16; ++i) {
            int r = rg * 16 + i;
            t[r][cx] = f2bf(W[(size_t)(r0 + r) * NC + c0 + cx]);
        }
        __syncthreads();
#pragma unroll
        for (int i = 0; i < 16; ++i) {
            int n = rg * 16 + i;
            O[(size_t)(c0 + n) * K + r0 + cx] = t[cx][n];
        }
    } else {
        int idx = (blk - 144) * 256 + tid;        // 8192 blocks: 2M mkey + misc
        if (idx < P_N * 1024) mkey[idx] = 0u;     // 0 < fkey(any real)
        if (idx < MROWS) keys[idx] = ~0ull;
        if (idx < 3072) stats[idx] = 0.0f;
    }
}

// ---- K1a: scan boundary points, per-bin min via packed u64 atomicMin --------
__global__ __launch_bounds__(256) void k_scan(
        const float* __restrict__ end_pos, const float* __restrict__ rel_pos,
        const float* __restrict__ bpts, unsigned long long* __restrict__ keys) {
    __shared__ unsigned long long s_key[NB];
    int tid = threadIdx.x;
    int p = blockIdx.x / SPLIT, part = blockIdx.x % SPLIT;
    if (tid < NB) s_key[tid] = ~0ull;
    __syncthreads();

    float ex = end_pos[2 * p], ey = end_pos[2 * p + 1];
    float rx = rel_pos[2 * p], ry = rel_pos[2 * p + 1];
    float rr = rx * rx + ry * ry;
    float c, s;
    if (rr > 0.0f) { float inv = 1.0f / sqrtf(rr); c = rx * inv; s = ry * inv; }
    else           { c = 1.0f; s = 0.0f; }

    const float T0 = -4.704630109f, T1 = -2.246036774f, T2 = -1.376381920f,
                T3 = -0.900404044f, T4 = -0.577350269f, T5 = -0.324919696f,
                T6 = -0.105104235f, T7 =  0.105104235f, T8 =  0.324919696f,
                T9 =  0.577350269f, T10 = 0.900404044f, T11 = 1.376381920f,
                T12 = 2.246036774f, T13 = 4.704630109f;

    const float2* bp2 = (const float2*)bpts;
    int bstart = part * BPB;
    for (int b = bstart + tid; b < bstart + BPB; b += 256) {
        float2 pt = bp2[b];
        float dx = pt.x - ex, dy = pt.y - ey;
        float xb = dx * c + dy * s;
        float yb = dy * c - dx * s;
        float r2 = xb * xb + yb * yb;
        bool v3 = yb > T7 * xb;
        float ta = v3 ? T11 : T3;
        bool v2 = yb > ta * xb;
        float tb = v3 ? (v2 ? T13 : T9) : (v2 ? T5 : T1);
        bool v1 = yb > tb * xb;
        float tc = v3 ? (v2 ? (v1 ? 3.0e38f : T12) : (v1 ? T10 : T8))
                      : (v2 ? (v1 ? T6 : T4)       : (v1 ? T2 : T0));
        bool v0 = yb > tc * xb;
        int bin = (v3 ? 8 : 0) + (v2 ? 4 : 0) + (v1 ? 2 : 0) + (v0 ? 1 : 0);
        if (xb > 0.0f) {
            unsigned long long key =
                ((unsigned long long)__float_as_uint(r2) << 32) | (unsigned int)b;
            atomicMin(&s_key[bin], key);
        }
    }
    __syncthreads();
    if (tid < NB) atomicMin(&keys[p * NB + tid], s_key[tid]);
}

// ---- K1b: choose point/fallback, build X = [emb(64) | h(64)] per (p,cell) ---
__global__ __launch_bounds__(256) void k_assemble(
        const unsigned long long* __restrict__ keys,
        const float* __restrict__ end_pos, const float* __restrict__ rel_pos,
        const float* __restrict__ bpts, const float* __restrict__ Wsp,
        const float* __restrict__ bsp, const float* __restrict__ h,
        unsigned short* __restrict__ X) {
    __shared__ float2 s_rel[NB];
    int p = blockIdx.x, tid = threadIdx.x;
    if (tid < NB) {
        float ex = end_pos[2 * p], ey = end_pos[2 * p + 1];
        unsigned long long key = keys[p * NB + tid];
        float r = sqrtf(__uint_as_float((unsigned int)(key >> 32)));
        float relx, rely;
        if (r <= 2.0f) {
            int b = (int)(key & 0xFFFFFFFFu);
            relx = bpts[2 * b] - ex; rely = bpts[2 * b + 1] - ey;
        } else {
            float rx = rel_pos[2 * p], ry = rel_pos[2 * p + 1];
            float rr = rx * rx + ry * ry;
            float c, s;
            if (rr > 0.0f) { float inv = 1.0f / sqrtf(rr); c = rx * inv; s = ry * inv; }
            else           { c = 1.0f; s = 0.0f; }
            float th = ((float)tid + 0.5f) * (float)(M_PI / 15.0) - (float)(M_PI / 2.0);
            float xc = 2.0f * cosf(th), yc = 2.0f * sinf(th);
            relx = xc * c - yc * s;
            rely = xc * s + yc * c;
        }
        s_rel[tid] = make_float2(relx, rely);
    }
    __syncthreads();
    if (tid < NB * 16) {
        int cell = tid >> 4, e0 = (tid & 15) * 8;
        float2 rel = s_rel[cell];
        unsigned short ubuf[8];
        if (e0 < 64) {
            float4 w0a = *(const float4*)(Wsp + e0),      w0b = *(const float4*)(Wsp + e0 + 4);
            float4 w1a = *(const float4*)(Wsp + 64 + e0), w1b = *(const float4*)(Wsp + 64 + e0 + 4);
            float4 bba = *(const float4*)(bsp + e0),      bbb = *(const float4*)(bsp + e0 + 4);
            float w0[8] = {w0a.x,w0a.y,w0a.z,w0a.w,w0b.x,w0b.y,w0b.z,w0b.w};
            float w1[8] = {w1a.x,w1a.y,w1a.z,w1a.w,w1b.x,w1b.y,w1b.z,w1b.w};
            float bb[8] = {bba.x,bba.y,bba.z,bba.w,bbb.x,bbb.y,bbb.z,bbb.w};
#pragma unroll
            for (int j = 0; j < 8; ++j)
                ubuf[j] = f2bf(rel.x * w0[j] + rel.y * w1[j] + bb[j]);
        } else {
            float4 ha = *(const float4*)(h + p * 64 + (e0 - 64));
            float4 hb = *(const float4*)(h + p * 64 + (e0 - 64) + 4);
            float hv[8] = {ha.x,ha.y,ha.z,ha.w,hb.x,hb.y,hb.z,hb.w};
#pragma unroll
            for (int j = 0; j < 8; ++j) ubuf[j] = f2bf(hv[j]);
        }
        *(uint4*)(X + ((size_t)p * NB + cell) * 128 + e0) = *(uint4*)ubuf;
    }
}

// ---- 256x256 GEMM, BK=32, 8 waves (2Mx4N), 3-buf distance-2 counted-vmcnt,
//      m201-style phase-lockstep: per K-step two phases, each
//      {issue 2 gld_lds -> ds_read subtile -> barrier -> setprio 16 MFMA
//       -> barrier}; vmcnt(4) only at the step boundary (never 0 mid-loop).
template<int K, bool WRITE_C>
__global__ __launch_bounds__(512) void k_gemm256(
        const unsigned short* __restrict__ A, const unsigned short* __restrict__ Bt,
        const float* __restrict__ bias, unsigned short* __restrict__ C,
        int N, float* __restrict__ osum, float* __restrict__ osq,
        unsigned int* __restrict__ mkey) {
    __shared__ __align__(16) unsigned short lds[49152];  // 3 bufs x 16384 (A|B)
    int tid = threadIdx.x;

    // XCD-grouped remap: blocks sharing an A-panel sit on one XCD's L2
    int nbt = N >> 8;
    int d = blockIdx.x;
    int m5 = d >> 3;
    int bn = m5 % nbt;
    int bm = (d & 7) + ((m5 / nbt) << 3);
    int row0 = bm << 8, col0 = bn << 8;

    int lane = tid & 63, wave = tid >> 6;
    int wr = wave >> 2, wc = wave & 3;
    int frow = lane & 15, kq = lane >> 4;

    f32x4 zero = {0.f, 0.f, 0.f, 0.f};
    f32x4 acc[8][4];
#pragma unroll
    for (int i = 0; i < 8; ++i)
#pragma unroll
        for (int j = 0; j < 4; ++j) acc[i][j] = zero;

    // staging: waves 0-3 stage A rows [w*64, w*64+64), waves 4-7 stage B rows.
    // chunk = 16 rows x 32 k in [kseg][row][8] (1KB, linear in lane order).
    const unsigned short* gsrc =
        (wave < 4) ? (A  + (size_t)(row0 + (wave << 6) + frow) * K + kq * 8)
                   : (Bt + (size_t)(col0 + ((wave - 4) << 6) + frow) * K + kq * 8);
    unsigned ldsbase = (unsigned)wave * 2048;   // waves 4-7 land in B region 8192+

    auto issue_half = [&](int t, int hf) {   // 2 gld_lds per wave
        unsigned short* dst = lds + (t % 3) * 16384 + ldsbase + hf * 1024;
        int ko = t * 32;
        gld_lds16(gsrc + ko + (size_t)(hf * 32) * K,      dst);
        gld_lds16(gsrc + ko + (size_t)(hf * 32 + 16) * K, dst + 512);
    };

    constexpr int NT = K / 32;
    static_assert(NT >= 2, "need >=2 K-tiles");

    // prologue: tiles 0 and 1 in flight; wait tile 0 only
    issue_half(0, 0); issue_half(0, 1);
    issue_half(1, 0); issue_half(1, 1);
    asm volatile("s_waitcnt vmcnt(4)" ::: "memory");
    __builtin_amdgcn_s_barrier();
    asm volatile("" ::: "memory");

#pragma unroll
    for (int t = 0; t < NT; ++t) {
        const unsigned short* buf = lds + (t % 3) * 16384;
        bf16x8 af[4], bfv[4];
        // ---- phase 0: rows-half 0 (B frags held for the whole step) ----
        if (t + 2 < NT) issue_half(t + 2, 0);
#pragma unroll
        for (int j = 0; j < 4; ++j)
            bfv[j] = *(const bf16x8*)&buf[8192 + (wc * 4 + j) * 512 + kq * 128 + frow * 8];
#pragma unroll
        for (int i = 0; i < 4; ++i)
            af[i] = *(const bf16x8*)&buf[(wr * 8 + i) * 512 + kq * 128 + frow * 8];
        __builtin_amdgcn_s_barrier();              // lockstep: all reads issued
        __builtin_amdgcn_s_setprio(1);
#pragma unroll
        for (int i = 0; i < 4; ++i)
#pragma unroll
            for (int j = 0; j < 4; ++j)
                acc[i][j] = __builtin_amdgcn_mfma_f32_16x16x32_bf16(af[i], bfv[j], acc[i][j], 0, 0, 0);
        __builtin_amdgcn_s_setprio(0);
        __builtin_amdgcn_s_barrier();
        // ---- phase 1: rows-half 1 ----
        if (t + 2 < NT) issue_half(t + 2, 1);
#pragma unroll
        for (int i = 0; i < 4; ++i)
            af[i] = *(const bf16x8*)&buf[(wr * 8 + 4 + i) * 512 + kq * 128 + frow * 8];
        __builtin_amdgcn_s_barrier();
        __builtin_amdgcn_s_setprio(1);
#pragma unroll
        for (int i = 0; i < 4; ++i)
#pragma unroll
            for (int j = 0; j < 4; ++j)
                acc[4 + i][j] = __builtin_amdgcn_mfma_f32_16x16x32_bf16(af[i], bfv[j], acc[4 + i][j], 0, 0, 0);
        __builtin_amdgcn_s_setprio(0);
        // ---- boundary: tile t+1 landed; tile t+2's 4 loads stay in flight ----
        if (t + 2 < NT) asm volatile("s_waitcnt vmcnt(4)" ::: "memory");
        else            asm volatile("s_waitcnt vmcnt(0)" ::: "memory");
        __builtin_amdgcn_s_barrier();
        asm volatile("" ::: "memory");
    }

    // ---- fused column stats (f32, pre-rounding) ----
    float bv[4];
#pragma unroll
    for (int j = 0; j < 4; ++j) bv[j] = bias[col0 + wc * 64 + j * 16 + frow];

#pragma unroll
    for (int j = 0; j < 4; ++j) {
        int col = col0 + wc * 64 + j * 16 + frow;
        float csum = 0.f, csq = 0.f;
#pragma unroll
        for (int i = 0; i < 8; ++i) {
#pragma unroll
            for (int r = 0; r < 4; ++r) {
                float y = acc[i][j][r] + bv[j];
                csum += y; csq = fmaf(y, y, csq);
            }
        }
        csum += __shfl_xor(csum, 16); csum += __shfl_xor(csum, 32);
        csq  += __shfl_xor(csq, 16);  csq  += __shfl_xor(csq, 32);
        if (lane < 16) { atomicAdd(&osum[col], csum); atomicAdd(&osq[col], csq); }
    }

    // ---- 4 bands of 64 rows: stage bf16(y) in LDS [64][264], then either
    //      coalesced C store (GEMM1) or per-ped max scan (GEMM2) ----
    unsigned short* ldsC = lds;     // 64*264 elems = 33 KB, main loop done
#pragma unroll
    for (int b = 0; b < 4; ++b) {
        __syncthreads();
        if (wr == (b >> 1)) {
#pragma unroll
            for (int j = 0; j < 4; ++j) {
#pragma unroll
                for (int ii = 0; ii < 4; ++ii) {
                    int i = (b & 1) * 4 + ii;
#pragma unroll
                    for (int r = 0; r < 4; ++r) {
                        float y = acc[i][j][r] + bv[j];
                        ldsC[(ii * 16 + kq * 4 + r) * 264 + wc * 64 + j * 16 + frow] = f2bf(y);
                    }
                }
            }
        }
        __syncthreads();
        if (WRITE_C) {
#pragma unroll
            for (int it = 0; it < 4; ++it) {
                int s = it * 512 + tid;          // 2048 uint4 = 64 rows x 256 cols
                int brow = s >> 5, seg = s & 31;
                *(uint4*)(C + (size_t)(row0 + b * 64 + brow) * N + col0 + seg * 8) =
                    *(const uint4*)&ldsC[brow * 264 + seg * 8];
            }
        } else {
            int col = tid & 255, half = tid >> 8;  // 2 threads per column
            int lrow0 = half * 32;
            int grow = row0 + b * 64 + lrow0;
            int curp = grow / 15;
            int rem = 15 - (grow - curp * 15);     // rows until ped boundary
            float mx = -3.0e38f;
#pragma unroll
            for (int r = 0; r < 32; ++r) {
                mx = fmaxf(mx, bf2f(ldsC[(lrow0 + r) * 264 + col]));
                if (--rem == 0) {
                    atomicMax(&mkey[(size_t)curp * 1024 + col0 + col], fkey(mx));
                    mx = -3.0e38f; ++curp; rem = 15;
                }
            }
            if (rem != 15)
                atomicMax(&mkey[(size_t)curp * 1024 + col0 + col], fkey(mx));
        }
    }
}

// ---- BN + ReLU, in place, column-resident streaming (N=512); inline coeffs --
__global__ __launch_bounds__(256) void k_bnrelu(unsigned short* __restrict__ Y,
        const float* __restrict__ s, const float* __restrict__ q,
        const float* __restrict__ g, const float* __restrict__ be) {
    int tid = threadIdx.x;
    int seg  = tid & 63;                 // 64 uint4 segments per 512-col row
    int roff = tid >> 6;                 // 4 row-phases
    int r0 = blockIdx.x * 32;
    int c0 = seg * 8;
    const float invN = 1.0f / (float)MROWS;
    float scv[8], shv[8];
#pragma unroll
    for (int j = 0; j < 8; ++j) {
        float m = s[c0 + j] * invN;
        float v = q[c0 + j] * invN - m * m;
        float k = g[c0 + j] * rsqrtf(v + 1e-5f);
        scv[j] = k; shv[j] = be[c0 + j] - m * k;
    }
    for (int r = r0 + roff; r < r0 + 32; r += 4) {
        unsigned short* p = Y + (size_t)r * 512 + c0;
        uint4 v = *(const uint4*)p;
        unsigned short* u = (unsigned short*)&v;
#pragma unroll
        for (int j = 0; j < 8; ++j) {
            float x = fmaf(bf2f(u[j]), scv[j], shv[j]);
            u[j] = f2bf(fmaxf(x, 0.0f));
        }
        *(uint4*)p = v;
    }
}

// ---- finalize: out = relu(sc2 * max_y + sh2) from u32-keyed maxima ----------
__global__ void k_bnfin(const unsigned int* __restrict__ mkey, const float* __restrict__ s2,
                        const float* __restrict__ q2, const float* __restrict__ g2,
                        const float* __restrict__ be2, float* __restrict__ out) {
    int idx = blockIdx.x * 256 + threadIdx.x;      // 2048*128 threads
    int p = idx >> 7, cb = idx & 127;
    int c0 = cb << 3;
    const float invN = 1.0f / (float)MROWS;
    float4 sa = *(const float4*)(s2 + c0),  sb = *(const float4*)(s2 + c0 + 4);
    float4 qa = *(const float4*)(q2 + c0),  qb = *(const float4*)(q2 + c0 + 4);
    float4 ga = *(const float4*)(g2 + c0),  gb = *(const float4*)(g2 + c0 + 4);
    float4 ea = *(const float4*)(be2 + c0), eb = *(const float4*)(be2 + c0 + 4);
    float sv[8] = {sa.x,sa.y,sa.z,sa.w,sb.x,sb.y,sb.z,sb.w};
    float qv[8] = {qa.x,qa.y,qa.z,qa.w,qb.x,qb.y,qb.z,qb.w};
    float gv[8] = {ga.x,ga.y,ga.z,ga.w,gb.x,gb.y,gb.z,gb.w};
    float ev[8] = {ea.x,ea.y,ea.z,ea.w,eb.x,eb.y,eb.z,eb.w};
    uint4 k0 = *(const uint4*)(mkey + (size_t)p * 1024 + c0);
    uint4 k1 = *(const uint4*)(mkey + (size_t)p * 1024 + c0 + 4);
    unsigned kv[8] = {k0.x,k0.y,k0.z,k0.w,k1.x,k1.y,k1.z,k1.w};
    float o[8];
#pragma unroll
    for (int j = 0; j < 8; ++j) {
        float m = sv[j] * invN;
        float v = qv[j] * invN - m * m;
        float k = gv[j] * rsqrtf(v + 1e-5f);
        float sh = ev[j] - m * k;
        o[j] = fmaxf(fmaf(funkey(kv[j]), k, sh), 0.0f);
    }
    float4 o0 = {o[0], o[1], o[2], o[3]};
    float4 o1 = {o[4], o[5], o[6], o[7]};
    *(float4*)(out + (size_t)p * 1024 + c0)     = o0;
    *(float4*)(out + (size_t)p * 1024 + c0 + 4) = o1;
}

extern "C" void kernel_launch(void* const* d_in, const int* in_sizes, int n_in,
                              void* d_out, int out_size, void* d_ws, size_t ws_size,
                              hipStream_t stream) {
    const float* h       = (const float*)d_in[0];
    const float* end_pos = (const float*)d_in[1];
    const float* rel_pos = (const float*)d_in[2];
    const float* bpts    = (const float*)d_in[3];
    const float* Wsp     = (const float*)d_in[4];
    const float* bsp     = (const float*)d_in[5];
    const float* W1      = (const float*)d_in[6];
    const float* b1      = (const float*)d_in[7];
    const float* g1      = (const float*)d_in[8];
    const float* be1     = (const float*)d_in[9];
    const float* W2      = (const float*)d_in[10];
    const float* b2      = (const float*)d_in[11];
    const float* g2      = (const float*)d_in[12];
    const float* be2     = (const float*)d_in[13];
    float* out = (float*)d_out;

    char* ws = (char*)d_ws;
    float* s1  = (float*)ws;                 // 3072 f32 zeroed by k_prep
    float* q1  = s1 + 512;
    float* s2  = q1 + 512;
    float* q2  = s2 + 1024;
    unsigned long long* keys = (unsigned long long*)(ws + 32768);      // [30720] u64
    unsigned int* mkey = (unsigned int*)(ws + 32768 + 245760);         // [2048*1024] u32
    unsigned short* w1t = (unsigned short*)(ws + 32768 + 245760 + 8388608); // [512][128]
    unsigned short* w2t = w1t + (size_t)512 * 128;                     // [1024][512]
    unsigned short* X   = w2t + (size_t)1024 * 512;                    // [30720][128]
    unsigned short* Y1  = X   + (size_t)MROWS * 128;                   // [30720][512]

    k_prep<<<144 + 8192, 256, 0, stream>>>(W1, W2, w1t, w2t, s1, keys, mkey);
    k_scan<<<P_N * SPLIT, 256, 0, stream>>>(end_pos, rel_pos, bpts, keys);
    k_assemble<<<P_N, 256, 0, stream>>>(keys, end_pos, rel_pos, bpts, Wsp, bsp, h, X);
    k_gemm256<128, true><<<(MROWS / 256) * (512 / 256), 512, 0, stream>>>(
        X, w1t, b1, Y1, 512, s1, q1, nullptr);
    k_bnrelu<<<MROWS / 32, 256, 0, stream>>>(Y1, s1, q1, g1, be1);
    k_gemm256<512, false><<<(MROWS / 256) * (1024 / 256), 512, 0, stream>>>(
        Y1, w2t, b2, nullptr, 1024, s2, q2, mkey);
    k_bnfin<<<(P_N * 128) / 256, 256, 0, stream>>>(mkey, s2, q2, g2, be2, out);
}

// Round 13
// 144.344 us; speedup vs baseline: 1.0027x; 1.0027x over previous
//
#include <hip/hip_runtime.h>
#include <hip/hip_bf16.h>
#include <math.h>

#define P_N   2048
#define B_N   10000
#define NB    15
#define MROWS (P_N * NB)   // 30720
#define SPLIT 5
#define BPB   (B_N / SPLIT)  // 2000 boundary points per scan block

typedef __bf16 bf16x8 __attribute__((ext_vector_type(8)));
typedef float  f32x4  __attribute__((ext_vector_type(4)));

__device__ __forceinline__ float bf2f(unsigned short u) {
    union { unsigned int i; float f; } v; v.i = ((unsigned int)u) << 16; return v.f;
}
__device__ __forceinline__ unsigned short f2bf(float f) {
    union { float f; unsigned int i; } v; v.f = f;
    unsigned int i = v.i;
    i += 0x7FFFu + ((i >> 16) & 1u);
    return (unsigned short)(i >> 16);
}
__device__ __forceinline__ void gld_lds16(const unsigned short* g, unsigned short* l) {
    __builtin_amdgcn_global_load_lds(
        (const __attribute__((address_space(1))) unsigned int*)g,
        (__attribute__((address_space(3))) unsigned int*)l, 16, 0, 0);
}
// monotone u32 key for f32 (x<y iff key(x)<key(y)); all real keys > 0
__device__ __forceinline__ unsigned fkey(float f) {
    unsigned b = __float_as_uint(f);
    return (b & 0x80000000u) ? ~b : (b | 0x80000000u);
}
__device__ __forceinline__ float funkey(unsigned key) {
    unsigned b = (key & 0x80000000u) ? (key ^ 0x80000000u) : ~key;
    return __uint_as_float(b);
}

// ---- K0: tiled transpose W1/W2 -> bf16 [N][K]; uint4-zero stats+mkey; keys --
__global__ __launch_bounds__(256) void k_prep(const float* __restrict__ W1,
        const float* __restrict__ W2, unsigned short* __restrict__ w1t,
        unsigned short* __restrict__ w2t, float* __restrict__ stats,
        unsigned long long* __restrict__ keys, unsigned int* __restrict__ mkey) {
    int blk = blockIdx.x, tid = threadIdx.x;
    if (blk < 144) {
        __shared__ unsigned short t[64][65];
        const float* W; unsigned short* O; int NC, K, tr, tc;
        if (blk < 16) { W = W1; O = w1t; NC = 512; K = 128; tr = blk & 1; tc = blk >> 1; }
        else { int b = blk - 16; W = W2; O = w2t; NC = 1024; K = 512; tr = b & 7; tc = b >> 3; }
        int r0 = tr * 64, c0 = tc * 64;
        int cx = tid & 63, rg = tid >> 6;
#pragma unroll
        for (int i = 0; i < 16; ++i) {
            int r = rg * 16 + i;
            t[r][cx] = f2bf(W[(size_t)(r0 + r) * NC + c0 + cx]);
        }
        __syncthreads();
#pragma unroll
        for (int i = 0; i < 16; ++i) {
            int n = rg * 16 + i;
            O[(size_t)(c0 + n) * K + r0 + cx] = t[cx][n];
        }
    } else {
        // stats (12288 B) + mkey (8388608 B) are CONTIGUOUS -> one zero range
        int zidx = (blk - 144) * 256 + tid;
        if (zidx < 525056) {                    // (12288+8388608)/16
            uint4 z = {0u, 0u, 0u, 0u};
            ((uint4*)stats)[zidx] = z;
        } else if (zidx < 540416) {             // + 245760/16 keys = ~0
            uint4 f = {~0u, ~0u, ~0u, ~0u};
            ((uint4*)keys)[zidx - 525056] = f;
        }
    }
}

// ---- K1a: scan boundary points, per-bin min via packed u64 atomicMin --------
__global__ __launch_bounds__(256) void k_scan(
        const float* __restrict__ end_pos, const float* __restrict__ rel_pos,
        const float* __restrict__ bpts, unsigned long long* __restrict__ keys) {
    __shared__ unsigned long long s_key[NB];
    int tid = threadIdx.x;
    int p = blockIdx.x / SPLIT, part = blockIdx.x % SPLIT;
    if (tid < NB) s_key[tid] = ~0ull;
    __syncthreads();

    float ex = end_pos[2 * p], ey = end_pos[2 * p + 1];
    float rx = rel_pos[2 * p], ry = rel_pos[2 * p + 1];
    float rr = rx * rx + ry * ry;
    float c, s;
    if (rr > 0.0f) { float inv = 1.0f / sqrtf(rr); c = rx * inv; s = ry * inv; }
    else           { c = 1.0f; s = 0.0f; }

    const float T0 = -4.704630109f, T1 = -2.246036774f, T2 = -1.376381920f,
                T3 = -0.900404044f, T4 = -0.577350269f, T5 = -0.324919696f,
                T6 = -0.105104235f, T7 =  0.105104235f, T8 =  0.324919696f,
                T9 =  0.577350269f, T10 = 0.900404044f, T11 = 1.376381920f,
                T12 = 2.246036774f, T13 = 4.704630109f;

    const float2* bp2 = (const float2*)bpts;
    int bstart = part * BPB;
    for (int b = bstart + tid; b < bstart + BPB; b += 256) {
        float2 pt = bp2[b];
        float dx = pt.x - ex, dy = pt.y - ey;
        float xb = dx * c + dy * s;
        float yb = dy * c - dx * s;
        float r2 = xb * xb + yb * yb;
        bool v3 = yb > T7 * xb;
        float ta = v3 ? T11 : T3;
        bool v2 = yb > ta * xb;
        float tb = v3 ? (v2 ? T13 : T9) : (v2 ? T5 : T1);
        bool v1 = yb > tb * xb;
        float tc = v3 ? (v2 ? (v1 ? 3.0e38f : T12) : (v1 ? T10 : T8))
                      : (v2 ? (v1 ? T6 : T4)       : (v1 ? T2 : T0));
        bool v0 = yb > tc * xb;
        int bin = (v3 ? 8 : 0) + (v2 ? 4 : 0) + (v1 ? 2 : 0) + (v0 ? 1 : 0);
        if (xb > 0.0f) {
            unsigned long long key =
                ((unsigned long long)__float_as_uint(r2) << 32) | (unsigned int)b;
            atomicMin(&s_key[bin], key);
        }
    }
    __syncthreads();
    if (tid < NB) atomicMin(&keys[p * NB + tid], s_key[tid]);
}

// ---- K1b: choose point/fallback, build X = [emb(64) | h(64)] per (p,cell) ---
__global__ __launch_bounds__(256) void k_assemble(
        const unsigned long long* __restrict__ keys,
        const float* __restrict__ end_pos, const float* __restrict__ rel_pos,
        const float* __restrict__ bpts, const float* __restrict__ Wsp,
        const float* __restrict__ bsp, const float* __restrict__ h,
        unsigned short* __restrict__ X) {
    __shared__ float2 s_rel[NB];
    int p = blockIdx.x, tid = threadIdx.x;
    if (tid < NB) {
        float ex = end_pos[2 * p], ey = end_pos[2 * p + 1];
        unsigned long long key = keys[p * NB + tid];
        float r = sqrtf(__uint_as_float((unsigned int)(key >> 32)));
        float relx, rely;
        if (r <= 2.0f) {
            int b = (int)(key & 0xFFFFFFFFu);
            relx = bpts[2 * b] - ex; rely = bpts[2 * b + 1] - ey;
        } else {
            float rx = rel_pos[2 * p], ry = rel_pos[2 * p + 1];
            float rr = rx * rx + ry * ry;
            float c, s;
            if (rr > 0.0f) { float inv = 1.0f / sqrtf(rr); c = rx * inv; s = ry * inv; }
            else           { c = 1.0f; s = 0.0f; }
            float th = ((float)tid + 0.5f) * (float)(M_PI / 15.0) - (float)(M_PI / 2.0);
            float xc = 2.0f * cosf(th), yc = 2.0f * sinf(th);
            relx = xc * c - yc * s;
            rely = xc * s + yc * c;
        }
        s_rel[tid] = make_float2(relx, rely);
    }
    __syncthreads();
    if (tid < NB * 16) {
        int cell = tid >> 4, e0 = (tid & 15) * 8;
        float2 rel = s_rel[cell];
        unsigned short ubuf[8];
        if (e0 < 64) {
            float4 w0a = *(const float4*)(Wsp + e0),      w0b = *(const float4*)(Wsp + e0 + 4);
            float4 w1a = *(const float4*)(Wsp + 64 + e0), w1b = *(const float4*)(Wsp + 64 + e0 + 4);
            float4 bba = *(const float4*)(bsp + e0),      bbb = *(const float4*)(bsp + e0 + 4);
            float w0[8] = {w0a.x,w0a.y,w0a.z,w0a.w,w0b.x,w0b.y,w0b.z,w0b.w};
            float w1[8] = {w1a.x,w1a.y,w1a.z,w1a.w,w1b.x,w1b.y,w1b.z,w1b.w};
            float bb[8] = {bba.x,bba.y,bba.z,bba.w,bbb.x,bbb.y,bbb.z,bbb.w};
#pragma unroll
            for (int j = 0; j < 8; ++j)
                ubuf[j] = f2bf(rel.x * w0[j] + rel.y * w1[j] + bb[j]);
        } else {
            float4 ha = *(const float4*)(h + p * 64 + (e0 - 64));
            float4 hb = *(const float4*)(h + p * 64 + (e0 - 64) + 4);
            float hv[8] = {ha.x,ha.y,ha.z,ha.w,hb.x,hb.y,hb.z,hb.w};
#pragma unroll
            for (int j = 0; j < 8; ++j) ubuf[j] = f2bf(hv[j]);
        }
        *(uint4*)(X + ((size_t)p * NB + cell) * 128 + e0) = *(uint4*)ubuf;
    }
}

// ---- 256x256 GEMM, BK=64, 8 waves (2Mx4N), m201-style subtile phases --------
// 2 K-tile buffers (128 KB). Phase p in {0..3} = (subtile s=p>>1, row-half).
// Per phase: ds_read frags -> issue 2 gld_lds (tile t+1, subtile s) ->
// barrier -> setprio(1) 16 MFMA setprio(0). Subtile entry (p=0,2):
// vmcnt(4)+barrier — the counted wait drains exactly the subtile about to be
// read (FIFO: it is the oldest 4 of 8 outstanding), keeping 4 loads in
// flight; vmcnt(0) only at the final subtile of the last tile.
template<int K, bool WRITE_C>
__global__ __launch_bounds__(512) void k_gemm256(
        const unsigned short* __restrict__ A, const unsigned short* __restrict__ Bt,
        const float* __restrict__ bias, unsigned short* __restrict__ C,
        int N, float* __restrict__ osum, float* __restrict__ osq,
        unsigned int* __restrict__ mkey) {
    __shared__ __align__(16) unsigned short lds[65536];  // 2 bufs x 32768 elems
    int tid = threadIdx.x;

    // XCD-grouped remap: blocks sharing an A-panel sit on one XCD's L2
    int nbt = N >> 8;
    int d = blockIdx.x;
    int m5 = d >> 3;
    int bn = m5 % nbt;
    int bm = (d & 7) + ((m5 / nbt) << 3);
    int row0 = bm << 8, col0 = bn << 8;

    int lane = tid & 63, wave = tid >> 6;
    int wr = wave >> 2, wc = wave & 3;
    int frow = lane & 15, kq = lane >> 4;

    f32x4 zero = {0.f, 0.f, 0.f, 0.f};
    f32x4 acc[8][4];
#pragma unroll
    for (int i = 0; i < 8; ++i)
#pragma unroll
        for (int j = 0; j < 4; ++j) acc[i][j] = zero;

    // staging: waves 0-3 stage A rows [w*64, w*64+64), waves 4-7 stage B rows.
    // Per buffer: [subtile s(2) x 16384 elems: A 0..8191 | B 8192..16383].
    // Chunk = 16 rows x 32 k, layout [kq][frow][8] (512 elems, linear in lane
    // order) — proven conflict-free (R9-R11, SQ_LDS_BANK_CONFLICT = 0).
    const unsigned short* gsrc =
        (wave < 4) ? (A  + (size_t)(row0 + (wave << 6) + frow) * K + kq * 8)
                   : (Bt + (size_t)(col0 + ((wave - 4) << 6) + frow) * K + kq * 8);
    unsigned regbase = (wave < 4) ? (unsigned)wave * 2048
                                  : 8192u + (unsigned)(wave - 4) * 2048;

    // issue chunk pair hp in {0,1} (rows hp*32..hp*32+31) of (tile t, subtile s)
    auto issue2 = [&](int t, int s, int hp) {
        unsigned short* dst = lds + (t & 1) * 32768 + s * 16384 + regbase + hp * 1024;
        const unsigned short* src = gsrc + t * 64 + s * 32 + (size_t)(hp * 32) * K;
        gld_lds16(src,                  dst);
        gld_lds16(src + (size_t)16 * K, dst + 512);
    };

    constexpr int NT = K / 64;
    static_assert(NT >= 2, "need >=2 K-tiles");

    // prologue: tile 0 fully issued (8 loads/wave)
    issue2(0, 0, 0); issue2(0, 0, 1); issue2(0, 1, 0); issue2(0, 1, 1);

#pragma unroll
    for (int t = 0; t < NT; ++t) {
        const unsigned short* buf = lds + (t & 1) * 32768;
        bool more = (t + 1 < NT);
#pragma unroll
        for (int s = 0; s < 2; ++s) {
            const unsigned short* sub = buf + s * 16384;
            // ---- subtile entry sync ----
            if (more || s == 0) asm volatile("s_waitcnt vmcnt(4)" ::: "memory");
            else                asm volatile("s_waitcnt vmcnt(0)" ::: "memory");
            __builtin_amdgcn_s_barrier();
            asm volatile("" ::: "memory");
            // ---- phase 2s: B frags (kept for both halves) + A rows 0-3 ----
            bf16x8 bfv[4], af[4];
#pragma unroll
            for (int j = 0; j < 4; ++j)
                bfv[j] = *(const bf16x8*)&sub[8192 + (wc * 4 + j) * 512 + kq * 128 + frow * 8];
#pragma unroll
            for (int i = 0; i < 4; ++i)
                af[i] = *(const bf16x8*)&sub[(wr * 8 + i) * 512 + kq * 128 + frow * 8];
            if (more) issue2(t + 1, s, 0);
            __builtin_amdgcn_s_barrier();
            asm volatile("" ::: "memory");
            __builtin_amdgcn_s_setprio(1);
#pragma unroll
            for (int i = 0; i < 4; ++i)
#pragma unroll
                for (int j = 0; j < 4; ++j)
                    acc[i][j] = __builtin_amdgcn_mfma_f32_16x16x32_bf16(af[i], bfv[j], acc[i][j], 0, 0, 0);
            __builtin_amdgcn_s_setprio(0);
            // ---- phase 2s+1: A rows 4-7 ----
#pragma unroll
            for (int i = 0; i < 4; ++i)
                af[i] = *(const bf16x8*)&sub[(wr * 8 + 4 + i) * 512 + kq * 128 + frow * 8];
            if (more) issue2(t + 1, s, 1);
            __builtin_amdgcn_s_barrier();
            asm volatile("" ::: "memory");
            __builtin_amdgcn_s_setprio(1);
#pragma unroll
            for (int i = 0; i < 4; ++i)
#pragma unroll
                for (int j = 0; j < 4; ++j)
                    acc[4 + i][j] = __builtin_amdgcn_mfma_f32_16x16x32_bf16(af[i], bfv[j], acc[4 + i][j], 0, 0, 0);
            __builtin_amdgcn_s_setprio(0);
        }
    }

    // ---- fused column stats (f32, pre-rounding) ----
    float bv[4];
#pragma unroll
    for (int j = 0; j < 4; ++j) bv[j] = bias[col0 + wc * 64 + j * 16 + frow];

#pragma unroll
    for (int j = 0; j < 4; ++j) {
        int col = col0 + wc * 64 + j * 16 + frow;
        float csum = 0.f, csq = 0.f;
#pragma unroll
        for (int i = 0; i < 8; ++i) {
#pragma unroll
            for (int r = 0; r < 4; ++r) {
                float y = acc[i][j][r] + bv[j];
                csum += y; csq = fmaf(y, y, csq);
            }
        }
        csum += __shfl_xor(csum, 16); csum += __shfl_xor(csum, 32);
        csq  += __shfl_xor(csq, 16);  csq  += __shfl_xor(csq, 32);
        if (lane < 16) { atomicAdd(&osum[col], csum); atomicAdd(&osq[col], csq); }
    }

    // ---- 4 bands of 64 rows: stage bf16(y) in LDS [64][264], then either
    //      coalesced C store (GEMM1) or per-ped max scan (GEMM2) ----
    unsigned short* ldsC = lds;     // 64*264 elems = 33 KB, main loop done
#pragma unroll
    for (int b = 0; b < 4; ++b) {
        __syncthreads();
        if (wr == (b >> 1)) {
#pragma unroll
            for (int j = 0; j < 4; ++j) {
#pragma unroll
                for (int ii = 0; ii < 4; ++ii) {
                    int i = (b & 1) * 4 + ii;
#pragma unroll
                    for (int r = 0; r < 4; ++r) {
                        float y = acc[i][j][r] + bv[j];
                        ldsC[(ii * 16 + kq * 4 + r) * 264 + wc * 64 + j * 16 + frow] = f2bf(y);
                    }
                }
            }
        }
        __syncthreads();
        if (WRITE_C) {
#pragma unroll
            for (int it = 0; it < 4; ++it) {
                int s = it * 512 + tid;          // 2048 uint4 = 64 rows x 256 cols
                int brow = s >> 5, seg = s & 31;
                *(uint4*)(C + (size_t)(row0 + b * 64 + brow) * N + col0 + seg * 8) =
                    *(const uint4*)&ldsC[brow * 264 + seg * 8];
            }
        } else {
            int col = tid & 255, half = tid >> 8;  // 2 threads per column
            int lrow0 = half * 32;
            int grow = row0 + b * 64 + lrow0;
            int curp = grow / 15;
            int rem = 15 - (grow - curp * 15);     // rows until ped boundary
            float mx = -3.0e38f;
#pragma unroll
            for (int r = 0; r < 32; ++r) {
                mx = fmaxf(mx, bf2f(ldsC[(lrow0 + r) * 264 + col]));
                if (--rem == 0) {
                    atomicMax(&mkey[(size_t)curp * 1024 + col0 + col], fkey(mx));
                    mx = -3.0e38f; ++curp; rem = 15;
                }
            }
            if (rem != 15)
                atomicMax(&mkey[(size_t)curp * 1024 + col0 + col], fkey(mx));
        }
    }
}

// ---- BN + ReLU, in place, column-resident streaming (N=512); inline coeffs --
__global__ __launch_bounds__(256) void k_bnrelu(unsigned short* __restrict__ Y,
        const float* __restrict__ s, const float* __restrict__ q,
        const float* __restrict__ g, const float* __restrict__ be) {
    int tid = threadIdx.x;
    int seg  = tid & 63;                 // 64 uint4 segments per 512-col row
    int roff = tid >> 6;                 // 4 row-phases
    int r0 = blockIdx.x * 32;
    int c0 = seg * 8;
    const float invN = 1.0f / (float)MROWS;
    float scv[8], shv[8];
#pragma unroll
    for (int j = 0; j < 8; ++j) {
        float m = s[c0 + j] * invN;
        float v = q[c0 + j] * invN - m * m;
        float k = g[c0 + j] * rsqrtf(v + 1e-5f);
        scv[j] = k; shv[j] = be[c0 + j] - m * k;
    }
    for (int r = r0 + roff; r < r0 + 32; r += 4) {
        unsigned short* p = Y + (size_t)r * 512 + c0;
        uint4 v = *(const uint4*)p;
        unsigned short* u = (unsigned short*)&v;
#pragma unroll
        for (int j = 0; j < 8; ++j) {
            float x = fmaf(bf2f(u[j]), scv[j], shv[j]);
            u[j] = f2bf(fmaxf(x, 0.0f));
        }
        *(uint4*)p = v;
    }
}

// ---- finalize: out = relu(sc2 * max_y + sh2) from u32-keyed maxima ----------
__global__ void k_bnfin(const unsigned int* __restrict__ mkey, const float* __restrict__ s2,
                        const float* __restrict__ q2, const float* __restrict__ g2,
                        const float* __restrict__ be2, float* __restrict__ out) {
    int idx = blockIdx.x * 256 + threadIdx.x;      // 2048*128 threads
    int p = idx >> 7, cb = idx & 127;
    int c0 = cb << 3;
    const float invN = 1.0f / (float)MROWS;
    float4 sa = *(const float4*)(s2 + c0),  sb = *(const float4*)(s2 + c0 + 4);
    float4 qa = *(const float4*)(q2 + c0),  qb = *(const float4*)(q2 + c0 + 4);
    float4 ga = *(const float4*)(g2 + c0),  gb = *(const float4*)(g2 + c0 + 4);
    float4 ea = *(const float4*)(be2 + c0), eb = *(const float4*)(be2 + c0 + 4);
    float sv[8] = {sa.x,sa.y,sa.z,sa.w,sb.x,sb.y,sb.z,sb.w};
    float qv[8] = {qa.x,qa.y,qa.z,qa.w,qb.x,qb.y,qb.z,qb.w};
    float gv[8] = {ga.x,ga.y,ga.z,ga.w,gb.x,gb.y,gb.z,gb.w};
    float ev[8] = {ea.x,ea.y,ea.z,ea.w,eb.x,eb.y,eb.z,eb.w};
    uint4 k0 = *(const uint4*)(mkey + (size_t)p * 1024 + c0);
    uint4 k1 = *(const uint4*)(mkey + (size_t)p * 1024 + c0 + 4);
    unsigned kv[8] = {k0.x,k0.y,k0.z,k0.w,k1.x,k1.y,k1.z,k1.w};
    float o[8];
#pragma unroll
    for (int j = 0; j < 8; ++j) {
        float m = sv[j] * invN;
        float v = qv[j] * invN - m * m;
        float k = gv[j] * rsqrtf(v + 1e-5f);
        float sh = ev[j] - m * k;
        o[j] = fmaxf(fmaf(funkey(kv[j]), k, sh), 0.0f);
    }
    float4 o0 = {o[0], o[1], o[2], o[3]};
    float4 o1 = {o[4], o[5], o[6], o[7]};
    *(float4*)(out + (size_t)p * 1024 + c0)     = o0;
    *(float4*)(out + (size_t)p * 1024 + c0 + 4) = o1;
}

extern "C" void kernel_launch(void* const* d_in, const int* in_sizes, int n_in,
                              void* d_out, int out_size, void* d_ws, size_t ws_size,
                              hipStream_t stream) {
    const float* h       = (const float*)d_in[0];
    const float* end_pos = (const float*)d_in[1];
    const float* rel_pos = (const float*)d_in[2];
    const float* bpts    = (const float*)d_in[3];
    const float* Wsp     = (const float*)d_in[4];
    const float* bsp     = (const float*)d_in[5];
    const float* W1      = (const float*)d_in[6];
    const float* b1      = (const float*)d_in[7];
    const float* g1      = (const float*)d_in[8];
    const float* be1     = (const float*)d_in[9];
    const float* W2      = (const float*)d_in[10];
    const float* b2      = (const float*)d_in[11];
    const float* g2      = (const float*)d_in[12];
    const float* be2     = (const float*)d_in[13];
    float* out = (float*)d_out;

    // ws layout: [stats 12288B][mkey 8388608B][keys 245760B][w1t][w2t][X][Y1]
    char* ws = (char*)d_ws;
    float* s1  = (float*)ws;
    float* q1  = s1 + 512;
    float* s2  = q1 + 512;
    float* q2  = s2 + 1024;
    unsigned int* mkey = (unsigned int*)(ws + 12288);
    unsigned long long* keys = (unsigned long long*)(ws + 12288 + 8388608);
    unsigned short* w1t = (unsigned short*)(ws + 12288 + 8388608 + 245760);
    unsigned short* w2t = w1t + (size_t)512 * 128;                     // [1024][512]
    unsigned short* X   = w2t + (size_t)1024 * 512;                    // [30720][128]
    unsigned short* Y1  = X   + (size_t)MROWS * 128;                   // [30720][512]

    k_prep<<<144 + 2111, 256, 0, stream>>>(W1, W2, w1t, w2t, s1, keys, mkey);
    k_scan<<<P_N * SPLIT, 256, 0, stream>>>(end_pos, rel_pos, bpts, keys);
    k_assemble<<<P_N, 256, 0, stream>>>(keys, end_pos, rel_pos, bpts, Wsp, bsp, h, X);
    k_gemm256<128, true><<<(MROWS / 256) * (512 / 256), 512, 0, stream>>>(
        X, w1t, b1, Y1, 512, s1, q1, nullptr);
    k_bnrelu<<<MROWS / 32, 256, 0, stream>>>(Y1, s1, q1, g1, be1);
    k_gemm256<512, false><<<(MROWS / 256) * (1024 / 256), 512, 0, stream>>>(
        Y1, w2t, b2, nullptr, 1024, s2, q2, mkey);
    k_bnfin<<<(P_N * 128) / 256, 256, 0, stream>>>(mkey, s2, q2, g2, be2, out);
}

// Round 14
// 143.990 us; speedup vs baseline: 1.0051x; 1.0025x over previous
//
#include <hip/hip_runtime.h>
#include <hip/hip_bf16.h>
#include <math.h>

#define P_N   2048
#define B_N   10000
#define NB    15
#define MROWS (P_N * NB)   // 30720
#define SPLIT 5
#define BPB   (B_N / SPLIT)  // 2000 boundary points per scan block

typedef __bf16 bf16x8 __attribute__((ext_vector_type(8)));
typedef float  f32x4  __attribute__((ext_vector_type(4)));

__device__ __forceinline__ float bf2f(unsigned short u) {
    union { unsigned int i; float f; } v; v.i = ((unsigned int)u) << 16; return v.f;
}
__device__ __forceinline__ unsigned short f2bf(float f) {
    union { float f; unsigned int i; } v; v.f = f;
    unsigned int i = v.i;
    i += 0x7FFFu + ((i >> 16) & 1u);
    return (unsigned short)(i >> 16);
}
__device__ __forceinline__ void gld_lds16(const unsigned short* g, unsigned short* l) {
    __builtin_amdgcn_global_load_lds(
        (const __attribute__((address_space(1))) unsigned int*)g,
        (__attribute__((address_space(3))) unsigned int*)l, 16, 0, 0);
}
// monotone u32 key for f32 (x<y iff key(x)<key(y)); all real keys > 0
__device__ __forceinline__ unsigned fkey(float f) {
    unsigned b = __float_as_uint(f);
    return (b & 0x80000000u) ? ~b : (b | 0x80000000u);
}
__device__ __forceinline__ float funkey(unsigned key) {
    unsigned b = (key & 0x80000000u) ? (key ^ 0x80000000u) : ~key;
    return __uint_as_float(b);
}

// ---- K0 (fused front): transpose W1/W2 -> bf16 [N][K]; zero stats+mkey;
//      boundary scan -> per-(part,ped,bin) min keys in EXCLUSIVE slots -------
__global__ __launch_bounds__(256) void k_front(const float* __restrict__ W1,
        const float* __restrict__ W2, unsigned short* __restrict__ w1t,
        unsigned short* __restrict__ w2t, float* __restrict__ stats,
        const float* __restrict__ end_pos, const float* __restrict__ rel_pos,
        const float* __restrict__ bpts, unsigned long long* __restrict__ pkeys) {
    __shared__ unsigned short t[64][65];
    __shared__ unsigned long long s_key[NB];
    int blk = blockIdx.x, tid = threadIdx.x;
    if (blk < 144) {                          // -------- weight transpose
        const float* W; unsigned short* O; int NC, K, tr, tc;
        if (blk < 16) { W = W1; O = w1t; NC = 512; K = 128; tr = blk & 1; tc = blk >> 1; }
        else { int b = blk - 16; W = W2; O = w2t; NC = 1024; K = 512; tr = b & 7; tc = b >> 3; }
        int r0 = tr * 64, c0 = tc * 64;
        int cx = tid & 63, rg = tid >> 6;
#pragma unroll
        for (int i = 0; i < 16; ++i) {
            int r = rg * 16 + i;
            t[r][cx] = f2bf(W[(size_t)(r0 + r) * NC + c0 + cx]);
        }
        __syncthreads();
#pragma unroll
        for (int i = 0; i < 16; ++i) {
            int n = rg * 16 + i;
            O[(size_t)(c0 + n) * K + r0 + cx] = t[cx][n];
        }
    } else if (blk < 2196) {                  // -------- zero stats+mkey (contig)
        int zidx = (blk - 144) * 256 + tid;
        if (zidx < 525056) {                  // (12288 + 8388608) / 16
            uint4 z = {0u, 0u, 0u, 0u};
            ((uint4*)stats)[zidx] = z;
        }
    } else {                                  // -------- polar scan (10240 blocks)
        int sb = blk - 2196;
        int p = sb / SPLIT, part = sb % SPLIT;
        if (tid < NB) s_key[tid] = ~0ull;
        __syncthreads();

        float ex = end_pos[2 * p], ey = end_pos[2 * p + 1];
        float rx = rel_pos[2 * p], ry = rel_pos[2 * p + 1];
        float rr = rx * rx + ry * ry;
        float c, s;
        if (rr > 0.0f) { float inv = 1.0f / sqrtf(rr); c = rx * inv; s = ry * inv; }
        else           { c = 1.0f; s = 0.0f; }

        const float T0 = -4.704630109f, T1 = -2.246036774f, T2 = -1.376381920f,
                    T3 = -0.900404044f, T4 = -0.577350269f, T5 = -0.324919696f,
                    T6 = -0.105104235f, T7 =  0.105104235f, T8 =  0.324919696f,
                    T9 =  0.577350269f, T10 = 0.900404044f, T11 = 1.376381920f,
                    T12 = 2.246036774f, T13 = 4.704630109f;

        const float2* bp2 = (const float2*)bpts;
        int bstart = part * BPB;
        for (int b = bstart + tid; b < bstart + BPB; b += 256) {
            float2 pt = bp2[b];
            float dx = pt.x - ex, dy = pt.y - ey;
            float xb = dx * c + dy * s;
            float yb = dy * c - dx * s;
            float r2 = xb * xb + yb * yb;
            bool v3 = yb > T7 * xb;
            float ta = v3 ? T11 : T3;
            bool v2 = yb > ta * xb;
            float tb = v3 ? (v2 ? T13 : T9) : (v2 ? T5 : T1);
            bool v1 = yb > tb * xb;
            float tc = v3 ? (v2 ? (v1 ? 3.0e38f : T12) : (v1 ? T10 : T8))
                          : (v2 ? (v1 ? T6 : T4)       : (v1 ? T2 : T0));
            bool v0 = yb > tc * xb;
            int bin = (v3 ? 8 : 0) + (v2 ? 4 : 0) + (v1 ? 2 : 0) + (v0 ? 1 : 0);
            if (xb > 0.0f) {
                unsigned long long key =
                    ((unsigned long long)__float_as_uint(r2) << 32) | (unsigned int)b;
                atomicMin(&s_key[bin], key);
            }
        }
        __syncthreads();
        if (tid < NB) pkeys[(size_t)part * MROWS + p * NB + tid] = s_key[tid];
    }
}

// ---- K1b: reduce over parts, choose point/fallback, build X -----------------
__global__ __launch_bounds__(256) void k_assemble(
        const unsigned long long* __restrict__ pkeys,
        const float* __restrict__ end_pos, const float* __restrict__ rel_pos,
        const float* __restrict__ bpts, const float* __restrict__ Wsp,
        const float* __restrict__ bsp, const float* __restrict__ h,
        unsigned short* __restrict__ X) {
    __shared__ float2 s_rel[NB];
    int p = blockIdx.x, tid = threadIdx.x;
    if (tid < NB) {
        float ex = end_pos[2 * p], ey = end_pos[2 * p + 1];
        unsigned long long key = ~0ull;
#pragma unroll
        for (int part = 0; part < SPLIT; ++part) {
            unsigned long long k = pkeys[(size_t)part * MROWS + p * NB + tid];
            key = (k < key) ? k : key;
        }
        float r = sqrtf(__uint_as_float((unsigned int)(key >> 32)));
        float relx, rely;
        if (r <= 2.0f) {
            int b = (int)(key & 0xFFFFFFFFu);
            relx = bpts[2 * b] - ex; rely = bpts[2 * b + 1] - ey;
        } else {
            float rx = rel_pos[2 * p], ry = rel_pos[2 * p + 1];
            float rr = rx * rx + ry * ry;
            float c, s;
            if (rr > 0.0f) { float inv = 1.0f / sqrtf(rr); c = rx * inv; s = ry * inv; }
            else           { c = 1.0f; s = 0.0f; }
            float th = ((float)tid + 0.5f) * (float)(M_PI / 15.0) - (float)(M_PI / 2.0);
            float xc = 2.0f * cosf(th), yc = 2.0f * sinf(th);
            relx = xc * c - yc * s;
            rely = xc * s + yc * c;
        }
        s_rel[tid] = make_float2(relx, rely);
    }
    __syncthreads();
    if (tid < NB * 16) {
        int cell = tid >> 4, e0 = (tid & 15) * 8;
        float2 rel = s_rel[cell];
        unsigned short ubuf[8];
        if (e0 < 64) {
            float4 w0a = *(const float4*)(Wsp + e0);
            float4 w0b = *(const float4*)(Wsp + e0 + 4);
            float4 w1a = *(const float4*)(Wsp + 64 + e0);
            float4 w1b = *(const float4*)(Wsp + 64 + e0 + 4);
            float4 bba = *(const float4*)(bsp + e0);
            float4 bbb = *(const float4*)(bsp + e0 + 4);
            float w0[8] = {w0a.x,w0a.y,w0a.z,w0a.w,w0b.x,w0b.y,w0b.z,w0b.w};
            float w1[8] = {w1a.x,w1a.y,w1a.z,w1a.w,w1b.x,w1b.y,w1b.z,w1b.w};
            float bb[8] = {bba.x,bba.y,bba.z,bba.w,bbb.x,bbb.y,bbb.z,bbb.w};
#pragma unroll
            for (int j = 0; j < 8; ++j)
                ubuf[j] = f2bf(rel.x * w0[j] + rel.y * w1[j] + bb[j]);
        } else {
            float4 ha = *(const float4*)(h + p * 64 + (e0 - 64));
            float4 hb = *(const float4*)(h + p * 64 + (e0 - 64) + 4);
            float hv[8] = {ha.x,ha.y,ha.z,ha.w,hb.x,hb.y,hb.z,hb.w};
#pragma unroll
            for (int j = 0; j < 8; ++j) ubuf[j] = f2bf(hv[j]);
        }
        *(uint4*)(X + ((size_t)p * NB + cell) * 128 + e0) = *(uint4*)ubuf;
    }
}

// ---- GEMM1: 128x256 tile, BK=32, 2-buf (48 KB -> 2 blocks/CU, TLP regime),
//      R9-proven loop order; fused column stats; LDS-staged C write ----------
__global__ __launch_bounds__(512) void k_gemm128(
        const unsigned short* __restrict__ A, const unsigned short* __restrict__ Bt,
        const float* __restrict__ bias, unsigned short* __restrict__ C,
        float* __restrict__ osum, float* __restrict__ osq) {
    constexpr int K = 128, N = 512;
    __shared__ __align__(16) unsigned short lds[24576];  // 2 x 12288 (A 4096 | B 8192)
    int tid = threadIdx.x;

    int d = blockIdx.x;                 // 480 blocks: tiles_m=240 x nbt=2
    int m5 = d >> 3;
    int bn = m5 & 1;
    int bm = (d & 7) + ((m5 >> 1) << 3);
    int row0 = bm << 7, col0 = bn << 8;

    int lane = tid & 63, wave = tid >> 6;
    int wr = wave >> 2, wc = wave & 3;         // per-wave out: 64 rows x 64 cols
    int frow = lane & 15, kq = lane >> 4;

    f32x4 zero = {0.f, 0.f, 0.f, 0.f};
    f32x4 acc[4][4];
#pragma unroll
    for (int i = 0; i < 4; ++i)
#pragma unroll
        for (int j = 0; j < 4; ++j) acc[i][j] = zero;

    // staging: waves 0-1 -> A rows [w*64,+64); waves 2-5 -> B rows; 6-7 idle
    bool stager = wave < 6;
    int su = (wave < 2) ? wave : (wave < 6 ? wave - 2 : 0);
    const unsigned short* gsrc =
        (wave < 2) ? (A  + (size_t)(row0 + (su << 6) + frow) * K + kq * 8)
                   : (Bt + (size_t)(col0 + (su << 6) + frow) * K + kq * 8);
    unsigned regbase = (wave < 2) ? (unsigned)su * 2048 : 4096u + (unsigned)su * 2048;

    auto issue = [&](int t) {           // 4 chunks (64 rows x 32 k) per staging wave
        if (!stager) return;
        unsigned short* dst = lds + (t & 1) * 12288 + regbase;
        const unsigned short* src = gsrc + t * 32;
        gld_lds16(src,                   dst);
        gld_lds16(src + (size_t)16 * K,  dst + 512);
        gld_lds16(src + (size_t)32 * K,  dst + 1024);
        gld_lds16(src + (size_t)48 * K,  dst + 1536);
    };

    issue(0);
    asm volatile("s_waitcnt vmcnt(0)" ::: "memory");
    __builtin_amdgcn_s_barrier();
    asm volatile("" ::: "memory");

#pragma unroll
    for (int t = 0; t < 4; ++t) {       // NT = K/32 = 4
        if (t + 1 < 4) issue(t + 1);
        const unsigned short* buf = lds + (t & 1) * 12288;
        bf16x8 af[4], bfv[4];
#pragma unroll
        for (int i = 0; i < 4; ++i)
            af[i] = *(const bf16x8*)&buf[(wr * 4 + i) * 512 + kq * 128 + frow * 8];
#pragma unroll
        for (int j = 0; j < 4; ++j)
            bfv[j] = *(const bf16x8*)&buf[4096 + (wc * 4 + j) * 512 + kq * 128 + frow * 8];
        __builtin_amdgcn_s_setprio(1);
#pragma unroll
        for (int i = 0; i < 4; ++i)
#pragma unroll
            for (int j = 0; j < 4; ++j)
                acc[i][j] = __builtin_amdgcn_mfma_f32_16x16x32_bf16(af[i], bfv[j], acc[i][j], 0, 0, 0);
        __builtin_amdgcn_s_setprio(0);
        asm volatile("s_waitcnt vmcnt(0)" ::: "memory");
        __builtin_amdgcn_s_barrier();
        asm volatile("" ::: "memory");
    }

    // ---- fused column stats ----
    float bv[4];
#pragma unroll
    for (int j = 0; j < 4; ++j) bv[j] = bias[col0 + wc * 64 + j * 16 + frow];
#pragma unroll
    for (int j = 0; j < 4; ++j) {
        int col = col0 + wc * 64 + j * 16 + frow;
        float csum = 0.f, csq = 0.f;
#pragma unroll
        for (int i = 0; i < 4; ++i) {
#pragma unroll
            for (int r = 0; r < 4; ++r) {
                float y = acc[i][j][r] + bv[j];
                csum += y; csq = fmaf(y, y, csq);
            }
        }
        csum += __shfl_xor(csum, 16); csum += __shfl_xor(csum, 32);
        csq  += __shfl_xor(csq, 16);  csq  += __shfl_xor(csq, 32);
        if (lane < 16) { atomicAdd(&osum[col], csum); atomicAdd(&osq[col], csq); }
    }

    // ---- C write: 2 bands of 64 rows (band b = wave-row-group wr==b) ----
    unsigned short* ldsC = lds;         // 64 x 264 = 16896 elems <= 24576
#pragma unroll
    for (int b = 0; b < 2; ++b) {
        __syncthreads();
        if (wr == b) {
#pragma unroll
            for (int j = 0; j < 4; ++j) {
#pragma unroll
                for (int i = 0; i < 4; ++i) {
#pragma unroll
                    for (int r = 0; r < 4; ++r) {
                        float y = acc[i][j][r] + bv[j];
                        ldsC[(i * 16 + kq * 4 + r) * 264 + wc * 64 + j * 16 + frow] = f2bf(y);
                    }
                }
            }
        }
        __syncthreads();
#pragma unroll
        for (int it = 0; it < 4; ++it) {
            int s = it * 512 + tid;          // 2048 uint4 = 64 rows x 256 cols
            int brow = s >> 5, seg = s & 31;
            *(uint4*)(C + (size_t)(row0 + b * 64 + brow) * N + col0 + seg * 8) =
                *(const uint4*)&ldsC[brow * 264 + seg * 8];
        }
    }
}

// ---- GEMM2: 256x256, BK=64, subtile-phase pipeline (R13-verified, 60 us) ----
template<int K, bool WRITE_C>
__global__ __launch_bounds__(512) void k_gemm256(
        const unsigned short* __restrict__ A, const unsigned short* __restrict__ Bt,
        const float* __restrict__ bias, unsigned short* __restrict__ C,
        int N, float* __restrict__ osum, float* __restrict__ osq,
        unsigned int* __restrict__ mkey) {
    __shared__ __align__(16) unsigned short lds[65536];  // 2 bufs x 32768 elems
    int tid = threadIdx.x;

    int nbt = N >> 8;
    int d = blockIdx.x;
    int m5 = d >> 3;
    int bn = m5 % nbt;
    int bm = (d & 7) + ((m5 / nbt) << 3);
    int row0 = bm << 8, col0 = bn << 8;

    int lane = tid & 63, wave = tid >> 6;
    int wr = wave >> 2, wc = wave & 3;
    int frow = lane & 15, kq = lane >> 4;

    f32x4 zero = {0.f, 0.f, 0.f, 0.f};
    f32x4 acc[8][4];
#pragma unroll
    for (int i = 0; i < 8; ++i)
#pragma unroll
        for (int j = 0; j < 4; ++j) acc[i][j] = zero;

    const unsigned short* gsrc =
        (wave < 4) ? (A  + (size_t)(row0 + (wave << 6) + frow) * K + kq * 8)
                   : (Bt + (size_t)(col0 + ((wave - 4) << 6) + frow) * K + kq * 8);
    unsigned regbase = (wave < 4) ? (unsigned)wave * 2048
                                  : 8192u + (unsigned)(wave - 4) * 2048;

    auto issue2 = [&](int t, int s, int hp) {
        unsigned short* dst = lds + (t & 1) * 32768 + s * 16384 + regbase + hp * 1024;
        const unsigned short* src = gsrc + t * 64 + s * 32 + (size_t)(hp * 32) * K;
        gld_lds16(src,                  dst);
        gld_lds16(src + (size_t)16 * K, dst + 512);
    };

    constexpr int NT = K / 64;
    static_assert(NT >= 2, "need >=2 K-tiles");

    issue2(0, 0, 0); issue2(0, 0, 1); issue2(0, 1, 0); issue2(0, 1, 1);

#pragma unroll
    for (int t = 0; t < NT; ++t) {
        const unsigned short* buf = lds + (t & 1) * 32768;
        bool more = (t + 1 < NT);
#pragma unroll
        for (int s = 0; s < 2; ++s) {
            const unsigned short* sub = buf + s * 16384;
            if (more || s == 0) asm volatile("s_waitcnt vmcnt(4)" ::: "memory");
            else                asm volatile("s_waitcnt vmcnt(0)" ::: "memory");
            __builtin_amdgcn_s_barrier();
            asm volatile("" ::: "memory");
            bf16x8 bfv[4], af[4];
#pragma unroll
            for (int j = 0; j < 4; ++j)
                bfv[j] = *(const bf16x8*)&sub[8192 + (wc * 4 + j) * 512 + kq * 128 + frow * 8];
#pragma unroll
            for (int i = 0; i < 4; ++i)
                af[i] = *(const bf16x8*)&sub[(wr * 8 + i) * 512 + kq * 128 + frow * 8];
            if (more) issue2(t + 1, s, 0);
            __builtin_amdgcn_s_barrier();
            asm volatile("" ::: "memory");
            __builtin_amdgcn_s_setprio(1);
#pragma unroll
            for (int i = 0; i < 4; ++i)
#pragma unroll
                for (int j = 0; j < 4; ++j)
                    acc[i][j] = __builtin_amdgcn_mfma_f32_16x16x32_bf16(af[i], bfv[j], acc[i][j], 0, 0, 0);
            __builtin_amdgcn_s_setprio(0);
#pragma unroll
            for (int i = 0; i < 4; ++i)
                af[i] = *(const bf16x8*)&sub[(wr * 8 + 4 + i) * 512 + kq * 128 + frow * 8];
            if (more) issue2(t + 1, s, 1);
            __builtin_amdgcn_s_barrier();
            asm volatile("" ::: "memory");
            __builtin_amdgcn_s_setprio(1);
#pragma unroll
            for (int i = 0; i < 4; ++i)
#pragma unroll
                for (int j = 0; j < 4; ++j)
                    acc[4 + i][j] = __builtin_amdgcn_mfma_f32_16x16x32_bf16(af[i], bfv[j], acc[4 + i][j], 0, 0, 0);
            __builtin_amdgcn_s_setprio(0);
        }
    }

    float bv[4];
#pragma unroll
    for (int j = 0; j < 4; ++j) bv[j] = bias[col0 + wc * 64 + j * 16 + frow];

#pragma unroll
    for (int j = 0; j < 4; ++j) {
        int col = col0 + wc * 64 + j * 16 + frow;
        float csum = 0.f, csq = 0.f;
#pragma unroll
        for (int i = 0; i < 8; ++i) {
#pragma unroll
            for (int r = 0; r < 4; ++r) {
                float y = acc[i][j][r] + bv[j];
                csum += y; csq = fmaf(y, y, csq);
            }
        }
        csum += __shfl_xor(csum, 16); csum += __shfl_xor(csum, 32);
        csq  += __shfl_xor(csq, 16);  csq  += __shfl_xor(csq, 32);
        if (lane < 16) { atomicAdd(&osum[col], csum); atomicAdd(&osq[col], csq); }
    }

    unsigned short* ldsC = lds;
#pragma unroll
    for (int b = 0; b < 4; ++b) {
        __syncthreads();
        if (wr == (b >> 1)) {
#pragma unroll
            for (int j = 0; j < 4; ++j) {
#pragma unroll
                for (int ii = 0; ii < 4; ++ii) {
                    int i = (b & 1) * 4 + ii;
#pragma unroll
                    for (int r = 0; r < 4; ++r) {
                        float y = acc[i][j][r] + bv[j];
                        ldsC[(ii * 16 + kq * 4 + r) * 264 + wc * 64 + j * 16 + frow] = f2bf(y);
                    }
                }
            }
        }
        __syncthreads();
        if (WRITE_C) {
#pragma unroll
            for (int it = 0; it < 4; ++it) {
                int s = it * 512 + tid;
                int brow = s >> 5, seg = s & 31;
                *(uint4*)(C + (size_t)(row0 + b * 64 + brow) * N + col0 + seg * 8) =
                    *(const uint4*)&ldsC[brow * 264 + seg * 8];
            }
        } else {
            int col = tid & 255, half = tid >> 8;
            int lrow0 = half * 32;
            int grow = row0 + b * 64 + lrow0;
            int curp = grow / 15;
            int rem = 15 - (grow - curp * 15);
            float mx = -3.0e38f;
#pragma unroll
            for (int r = 0; r < 32; ++r) {
                mx = fmaxf(mx, bf2f(ldsC[(lrow0 + r) * 264 + col]));
                if (--rem == 0) {
                    atomicMax(&mkey[(size_t)curp * 1024 + col0 + col], fkey(mx));
                    mx = -3.0e38f; ++curp; rem = 15;
                }
            }
            if (rem != 15)
                atomicMax(&mkey[(size_t)curp * 1024 + col0 + col], fkey(mx));
        }
    }
}

// ---- BN + ReLU, in place, column-resident streaming (N=512); inline coeffs --
__global__ __launch_bounds__(256) void k_bnrelu(unsigned short* __restrict__ Y,
        const float* __restrict__ s, const float* __restrict__ q,
        const float* __restrict__ g, const float* __restrict__ be) {
    int tid = threadIdx.x;
    int seg  = tid & 63;
    int roff = tid >> 6;
    int r0 = blockIdx.x * 32;
    int c0 = seg * 8;
    const float invN = 1.0f / (float)MROWS;
    float scv[8], shv[8];
#pragma unroll
    for (int j = 0; j < 8; ++j) {
        float m = s[c0 + j] * invN;
        float v = q[c0 + j] * invN - m * m;
        float k = g[c0 + j] * rsqrtf(v + 1e-5f);
        scv[j] = k; shv[j] = be[c0 + j] - m * k;
    }
    for (int r = r0 + roff; r < r0 + 32; r += 4) {
        unsigned short* p = Y + (size_t)r * 512 + c0;
        uint4 v = *(const uint4*)p;
        unsigned short* u = (unsigned short*)&v;
#pragma unroll
        for (int j = 0; j < 8; ++j) {
            float x = fmaf(bf2f(u[j]), scv[j], shv[j]);
            u[j] = f2bf(fmaxf(x, 0.0f));
        }
        *(uint4*)p = v;
    }
}

// ---- finalize: out = relu(sc2 * max_y + sh2) from u32-keyed maxima ----------
__global__ void k_bnfin(const unsigned int* __restrict__ mkey, const float* __restrict__ s2,
                        const float* __restrict__ q2, const float* __restrict__ g2,
                        const float* __restrict__ be2, float* __restrict__ out) {
    int idx = blockIdx.x * 256 + threadIdx.x;
    int p = idx >> 7, cb = idx & 127;
    int c0 = cb << 3;
    const float invN = 1.0f / (float)MROWS;
    float4 sa = *(const float4*)(s2 + c0),  sb = *(const float4*)(s2 + c0 + 4);
    float4 qa = *(const float4*)(q2 + c0),  qb = *(const float4*)(q2 + c0 + 4);
    float4 ga = *(const float4*)(g2 + c0),  gb = *(const float4*)(g2 + c0 + 4);
    float4 ea = *(const float4*)(be2 + c0), eb = *(const float4*)(be2 + c0 + 4);
    float sv[8] = {sa.x,sa.y,sa.z,sa.w,sb.x,sb.y,sb.z,sb.w};
    float qv[8] = {qa.x,qa.y,qa.z,qa.w,qb.x,qb.y,qb.z,qb.w};
    float gv[8] = {ga.x,ga.y,ga.z,ga.w,gb.x,gb.y,gb.z,gb.w};
    float ev[8] = {ea.x,ea.y,ea.z,ea.w,eb.x,eb.y,eb.z,eb.w};
    uint4 k0 = *(const uint4*)(mkey + (size_t)p * 1024 + c0);
    uint4 k1 = *(const uint4*)(mkey + (size_t)p * 1024 + c0 + 4);
    unsigned kv[8] = {k0.x,k0.y,k0.z,k0.w,k1.x,k1.y,k1.z,k1.w};
    float o[8];
#pragma unroll
    for (int j = 0; j < 8; ++j) {
        float m = sv[j] * invN;
        float v = qv[j] * invN - m * m;
        float k = gv[j] * rsqrtf(v + 1e-5f);
        float sh = ev[j] - m * k;
        o[j] = fmaxf(fmaf(funkey(kv[j]), k, sh), 0.0f);
    }
    float4 o0 = {o[0], o[1], o[2], o[3]};
    float4 o1 = {o[4], o[5], o[6], o[7]};
    *(float4*)(out + (size_t)p * 1024 + c0)     = o0;
    *(float4*)(out + (size_t)p * 1024 + c0 + 4) = o1;
}

extern "C" void kernel_launch(void* const* d_in, const int* in_sizes, int n_in,
                              void* d_out, int out_size, void* d_ws, size_t ws_size,
                              hipStream_t stream) {
    const float* h       = (const float*)d_in[0];
    const float* end_pos = (const float*)d_in[1];
    const float* rel_pos = (const float*)d_in[2];
    const float* bpts    = (const float*)d_in[3];
    const float* Wsp     = (const float*)d_in[4];
    const float* bsp     = (const float*)d_in[5];
    const float* W1      = (const float*)d_in[6];
    const float* b1      = (const float*)d_in[7];
    const float* g1      = (const float*)d_in[8];
    const float* be1     = (const float*)d_in[9];
    const float* W2      = (const float*)d_in[10];
    const float* b2      = (const float*)d_in[11];
    const float* g2      = (const float*)d_in[12];
    const float* be2     = (const float*)d_in[13];
    float* out = (float*)d_out;

    // ws: [stats 12288][mkey 8388608][pkeys 1228800][w1t][w2t][X][Y1]
    char* ws = (char*)d_ws;
    float* s1  = (float*)ws;
    float* q1  = s1 + 512;
    float* s2  = q1 + 512;
    float* q2  = s2 + 1024;
    unsigned int* mkey = (unsigned int*)(ws + 12288);
    unsigned long long* pkeys = (unsigned long long*)(ws + 12288 + 8388608);
    unsigned short* w1t = (unsigned short*)(ws + 12288 + 8388608 + 1228800);
    unsigned short* w2t = w1t + (size_t)512 * 128;
    unsigned short* X   = w2t + (size_t)1024 * 512;
    unsigned short* Y1  = X   + (size_t)MROWS * 128;

    k_front<<<2196 + P_N * SPLIT, 256, 0, stream>>>(
        W1, W2, w1t, w2t, s1, end_pos, rel_pos, bpts, pkeys);
    k_assemble<<<P_N, 256, 0, stream>>>(pkeys, end_pos, rel_pos, bpts, Wsp, bsp, h, X);
    k_gemm128<<<480, 512, 0, stream>>>(X, w1t, b1, Y1, s1, q1);
    k_bnrelu<<<MROWS / 32, 256, 0, stream>>>(Y1, s1, q1, g1, be1);
    k_gemm256<512, false><<<(MROWS / 256) * (1024 / 256), 512, 0, stream>>>(
        Y1, w2t, b2, nullptr, 1024, s2, q2, mkey);
    k_bnfin<<<(P_N * 128) / 256, 256, 0, stream>>>(mkey, s2, q2, g2, be2, out);
}

// Round 15
// 136.119 us; speedup vs baseline: 1.0632x; 1.0578x over previous
//
#include <hip/hip_runtime.h>
#include <hip/hip_bf16.h>
#include <math.h>

#define P_N   2048
#define B_N   10000
#define NB    15
#define MROWS (P_N * NB)   // 30720
#define SPLIT 5
#define BPB   (B_N / SPLIT)  // 2000 boundary points per scan block

typedef __bf16 bf16x8 __attribute__((ext_vector_type(8)));
typedef float  f32x4  __attribute__((ext_vector_type(4)));

__device__ __forceinline__ float bf2f(unsigned short u) {
    union { unsigned int i; float f; } v; v.i = ((unsigned int)u) << 16; return v.f;
}
__device__ __forceinline__ unsigned short f2bf(float f) {
    union { float f; unsigned int i; } v; v.f = f;
    unsigned int i = v.i;
    i += 0x7FFFu + ((i >> 16) & 1u);
    return (unsigned short)(i >> 16);
}
__device__ __forceinline__ void gld_lds16(const unsigned short* g, unsigned short* l) {
    __builtin_amdgcn_global_load_lds(
        (const __attribute__((address_space(1))) unsigned int*)g,
        (__attribute__((address_space(3))) unsigned int*)l, 16, 0, 0);
}
// monotone u32 key for f32 (x<y iff key(x)<key(y)); all real keys > 0
__device__ __forceinline__ unsigned fkey(float f) {
    unsigned b = __float_as_uint(f);
    return (b & 0x80000000u) ? ~b : (b | 0x80000000u);
}
__device__ __forceinline__ float funkey(unsigned key) {
    unsigned b = (key & 0x80000000u) ? (key ^ 0x80000000u) : ~key;
    return __uint_as_float(b);
}

// ---- K0 (fused front): W1/W2 transpose; zero stats+mkey; V/c precompute;
//      h -> bf16; boundary scan -> exclusive per-(part,ped,bin) min keys -----
// block ranges: [0,144) transpose | [144,2196) zero | [2196,2198) V/c |
//               [2198,2326) hbf | [2326,12566) scan
__global__ __launch_bounds__(256) void k_front(const float* __restrict__ W1,
        const float* __restrict__ W2, unsigned short* __restrict__ w1t,
        unsigned short* __restrict__ w2t, float* __restrict__ stats,
        const float* __restrict__ end_pos, const float* __restrict__ rel_pos,
        const float* __restrict__ bpts, unsigned long long* __restrict__ pkeys,
        const float* __restrict__ h, unsigned short* __restrict__ hbf,
        const float* __restrict__ Wsp, const float* __restrict__ bsp,
        const float* __restrict__ b1, float* __restrict__ V0,
        float* __restrict__ V1, float* __restrict__ cvec) {
    __shared__ unsigned short t[64][65];
    __shared__ unsigned long long s_key[NB];
    int blk = blockIdx.x, tid = threadIdx.x;
    if (blk < 144) {                          // -------- weight transpose
        const float* W; unsigned short* O; int NC, K, tr, tc;
        if (blk < 16) { W = W1; O = w1t; NC = 512; K = 128; tr = blk & 1; tc = blk >> 1; }
        else { int b = blk - 16; W = W2; O = w2t; NC = 1024; K = 512; tr = b & 7; tc = b >> 3; }
        int r0 = tr * 64, c0 = tc * 64;
        int cx = tid & 63, rg = tid >> 6;
#pragma unroll
        for (int i = 0; i < 16; ++i) {
            int r = rg * 16 + i;
            t[r][cx] = f2bf(W[(size_t)(r0 + r) * NC + c0 + cx]);
        }
        __syncthreads();
#pragma unroll
        for (int i = 0; i < 16; ++i) {
            int n = rg * 16 + i;
            O[(size_t)(c0 + n) * K + r0 + cx] = t[cx][n];
        }
    } else if (blk < 2196) {                  // -------- zero stats+mkey (contig)
        int zidx = (blk - 144) * 256 + tid;
        if (zidx < 525056) {                  // (12288 + 8388608) / 16
            uint4 z = {0u, 0u, 0u, 0u};
            ((uint4*)stats)[zidx] = z;
        }
    } else if (blk < 2198) {                  // -------- V = Wsp@W1_top, c
        int col = (blk - 2196) * 256 + tid;   // 0..511
        float v0 = 0.f, v1 = 0.f, cc = 0.f;
        for (int e = 0; e < 64; ++e) {
            float w = W1[(size_t)e * 512 + col];
            v0 = fmaf(Wsp[e], w, v0);
            v1 = fmaf(Wsp[64 + e], w, v1);
            cc = fmaf(bsp[e], w, cc);
        }
        V0[col] = v0; V1[col] = v1; cvec[col] = cc + b1[col];
    } else if (blk < 2326) {                  // -------- h -> bf16 (2048x64)
        int base = (blk - 2198) * 1024 + tid * 4;
        float4 hv = *(const float4*)(h + base);
        unsigned short ub[4] = {f2bf(hv.x), f2bf(hv.y), f2bf(hv.z), f2bf(hv.w)};
        *(uint2*)(hbf + base) = *(uint2*)ub;
    } else {                                  // -------- polar scan (10240 blocks)
        int sb = blk - 2326;
        int p = sb / SPLIT, part = sb % SPLIT;
        if (tid < NB) s_key[tid] = ~0ull;
        __syncthreads();

        float ex = end_pos[2 * p], ey = end_pos[2 * p + 1];
        float rx = rel_pos[2 * p], ry = rel_pos[2 * p + 1];
        float rr = rx * rx + ry * ry;
        float c, s;
        if (rr > 0.0f) { float inv = 1.0f / sqrtf(rr); c = rx * inv; s = ry * inv; }
        else           { c = 1.0f; s = 0.0f; }

        const float T0 = -4.704630109f, T1 = -2.246036774f, T2 = -1.376381920f,
                    T3 = -0.900404044f, T4 = -0.577350269f, T5 = -0.324919696f,
                    T6 = -0.105104235f, T7 =  0.105104235f, T8 =  0.324919696f,
                    T9 =  0.577350269f, T10 = 0.900404044f, T11 = 1.376381920f,
                    T12 = 2.246036774f, T13 = 4.704630109f;

        const float2* bp2 = (const float2*)bpts;
        int bstart = part * BPB;
        for (int b = bstart + tid; b < bstart + BPB; b += 256) {
            float2 pt = bp2[b];
            float dx = pt.x - ex, dy = pt.y - ey;
            float xb = dx * c + dy * s;
            float yb = dy * c - dx * s;
            float r2 = xb * xb + yb * yb;
            bool v3 = yb > T7 * xb;
            float ta = v3 ? T11 : T3;
            bool v2 = yb > ta * xb;
            float tb = v3 ? (v2 ? T13 : T9) : (v2 ? T5 : T1);
            bool v1 = yb > tb * xb;
            float tc = v3 ? (v2 ? (v1 ? 3.0e38f : T12) : (v1 ? T10 : T8))
                          : (v2 ? (v1 ? T6 : T4)       : (v1 ? T2 : T0));
            bool v0 = yb > tc * xb;
            int bin = (v3 ? 8 : 0) + (v2 ? 4 : 0) + (v1 ? 2 : 0) + (v0 ? 1 : 0);
            if (xb > 0.0f) {
                unsigned long long key =
                    ((unsigned long long)__float_as_uint(r2) << 32) | (unsigned int)b;
                atomicMin(&s_key[bin], key);
            }
        }
        __syncthreads();
        if (tid < NB) pkeys[(size_t)part * MROWS + p * NB + tid] = s_key[tid];
    }
}

// ---- K1: reduce parts, choose point/fallback, emit rel (30720 x 2 f32) ------
__global__ __launch_bounds__(64) void k_assemble(
        const unsigned long long* __restrict__ pkeys,
        const float* __restrict__ end_pos, const float* __restrict__ rel_pos,
        const float* __restrict__ bpts, float* __restrict__ rel) {
    int p = blockIdx.x, tid = threadIdx.x;
    if (tid < NB) {
        float ex = end_pos[2 * p], ey = end_pos[2 * p + 1];
        unsigned long long key = ~0ull;
#pragma unroll
        for (int part = 0; part < SPLIT; ++part) {
            unsigned long long k = pkeys[(size_t)part * MROWS + p * NB + tid];
            key = (k < key) ? k : key;
        }
        float r = sqrtf(__uint_as_float((unsigned int)(key >> 32)));
        float relx, rely;
        if (r <= 2.0f) {
            int b = (int)(key & 0xFFFFFFFFu);
            relx = bpts[2 * b] - ex; rely = bpts[2 * b + 1] - ey;
        } else {
            float rx = rel_pos[2 * p], ry = rel_pos[2 * p + 1];
            float rr = rx * rx + ry * ry;
            float c, s;
            if (rr > 0.0f) { float inv = 1.0f / sqrtf(rr); c = rx * inv; s = ry * inv; }
            else           { c = 1.0f; s = 0.0f; }
            float th = ((float)tid + 0.5f) * (float)(M_PI / 15.0) - (float)(M_PI / 2.0);
            float xc = 2.0f * cosf(th), yc = 2.0f * sinf(th);
            relx = xc * c - yc * s;
            rely = xc * s + yc * c;
        }
        rel[(size_t)(p * NB + tid) * 2]     = relx;
        rel[(size_t)(p * NB + tid) * 2 + 1] = rely;
    }
}

// ---- K2: H' = hbf @ W1_bot^T  (2048 x 512, K=64), f32 out -------------------
__global__ __launch_bounds__(512) void k_hgemm(const unsigned short* __restrict__ hbf,
        const unsigned short* __restrict__ w1t, float* __restrict__ Hp) {
    __shared__ __align__(16) unsigned short lds[24576];  // 2 subtiles x (A 4096|B 8192)
    int tid = threadIdx.x;
    int bm = blockIdx.x & 15, bnn = blockIdx.x >> 4;     // 16 x 2 blocks
    int row0 = bm << 7, col0 = bnn << 8;
    int lane = tid & 63, wave = tid >> 6;
    int wr = wave >> 2, wc = wave & 3;                   // wave out: 64r x 64c
    int frow = lane & 15, kq = lane >> 4;

    f32x4 zero = {0.f, 0.f, 0.f, 0.f};
    f32x4 acc[4][4];
#pragma unroll
    for (int i = 0; i < 4; ++i)
#pragma unroll
        for (int j = 0; j < 4; ++j) acc[i][j] = zero;

    // 48 chunks (16r x 32k, [kq][frow][8]); wave w stages ch = w*6+k
#pragma unroll
    for (int k = 0; k < 6; ++k) {
        int ch = wave * 6 + k;
        int s = (ch >= 24) ? 1 : 0;
        int r = ch - s * 24;
        unsigned short* dst = lds + s * 12288 + r * 512;
        const unsigned short* src =
            (r < 8) ? (hbf + (size_t)(row0 + r * 16 + frow) * 64 + s * 32 + kq * 8)
                    : (w1t + (size_t)(col0 + (r - 8) * 16 + frow) * 128 + 64 + s * 32 + kq * 8);
        gld_lds16(src, dst);
    }
    asm volatile("s_waitcnt vmcnt(0)" ::: "memory");
    __builtin_amdgcn_s_barrier();
    asm volatile("" ::: "memory");

#pragma unroll
    for (int s = 0; s < 2; ++s) {
        const unsigned short* sub = lds + s * 12288;
        bf16x8 af[4], bfv[4];
#pragma unroll
        for (int i = 0; i < 4; ++i)
            af[i] = *(const bf16x8*)&sub[(wr * 4 + i) * 512 + kq * 128 + frow * 8];
#pragma unroll
        for (int j = 0; j < 4; ++j)
            bfv[j] = *(const bf16x8*)&sub[4096 + (wc * 4 + j) * 512 + kq * 128 + frow * 8];
#pragma unroll
        for (int i = 0; i < 4; ++i)
#pragma unroll
            for (int j = 0; j < 4; ++j)
                acc[i][j] = __builtin_amdgcn_mfma_f32_16x16x32_bf16(af[i], bfv[j], acc[i][j], 0, 0, 0);
    }

#pragma unroll
    for (int i = 0; i < 4; ++i)
#pragma unroll
        for (int j = 0; j < 4; ++j)
#pragma unroll
            for (int r = 0; r < 4; ++r) {
                int row = row0 + wr * 64 + i * 16 + kq * 4 + r;
                int col = col0 + wc * 64 + j * 16 + frow;
                Hp[(size_t)row * 512 + col] = acc[i][j][r];
            }
}

// ---- K3: BN1 stats by on-the-fly recompute: y = relx*V0 + rely*V1 + (c+H') --
__global__ __launch_bounds__(256) void k_stat1(const float* __restrict__ Hp,
        const float* __restrict__ rel, const float* __restrict__ V0,
        const float* __restrict__ V1, const float* __restrict__ cvec,
        float* __restrict__ s1, float* __restrict__ q1) {
    __shared__ float s_s[512], s_q[512];
    int tid = threadIdx.x;
    int pi = tid >> 6, seg = tid & 63;
    int p = blockIdx.x * 4 + pi;
    s_s[tid] = 0.f; s_s[tid + 256] = 0.f;
    s_q[tid] = 0.f; s_q[tid + 256] = 0.f;
    __syncthreads();

    float4 ha = *(const float4*)(Hp + (size_t)p * 512 + seg * 8);
    float4 hb = *(const float4*)(Hp + (size_t)p * 512 + seg * 8 + 4);
    float4 ca = *(const float4*)(cvec + seg * 8);
    float4 cb = *(const float4*)(cvec + seg * 8 + 4);
    float4 va = *(const float4*)(V0 + seg * 8), vb = *(const float4*)(V0 + seg * 8 + 4);
    float4 wa = *(const float4*)(V1 + seg * 8), wb = *(const float4*)(V1 + seg * 8 + 4);
    float hc[8] = {ha.x+ca.x, ha.y+ca.y, ha.z+ca.z, ha.w+ca.w,
                   hb.x+cb.x, hb.y+cb.y, hb.z+cb.z, hb.w+cb.w};
    float v0[8] = {va.x,va.y,va.z,va.w,vb.x,vb.y,vb.z,vb.w};
    float v1[8] = {wa.x,wa.y,wa.z,wa.w,wb.x,wb.y,wb.z,wb.w};
    float ss[8] = {0,0,0,0,0,0,0,0}, qq[8] = {0,0,0,0,0,0,0,0};
#pragma unroll
    for (int cell = 0; cell < NB; ++cell) {
        float2 rl = *(const float2*)(rel + (size_t)(p * NB + cell) * 2);
#pragma unroll
        for (int j = 0; j < 8; ++j) {
            float y = fmaf(rl.x, v0[j], fmaf(rl.y, v1[j], hc[j]));
            ss[j] += y; qq[j] = fmaf(y, y, qq[j]);
        }
    }
#pragma unroll
    for (int j = 0; j < 8; ++j) {
        atomicAdd(&s_s[seg * 8 + j], ss[j]);
        atomicAdd(&s_q[seg * 8 + j], qq[j]);
    }
    __syncthreads();
    atomicAdd(&s1[tid], s_s[tid]);
    atomicAdd(&s1[tid + 256], s_s[tid + 256]);
    atomicAdd(&q1[tid], s_q[tid]);
    atomicAdd(&q1[tid + 256], s_q[tid + 256]);
}

// ---- K4: BN1 coefficients ----------------------------------------------------
__global__ void k_coef1(const float* __restrict__ s1, const float* __restrict__ q1,
                        const float* __restrict__ g1, const float* __restrict__ be1,
                        float* __restrict__ sc1, float* __restrict__ sh1) {
    int i = blockIdx.x * 256 + threadIdx.x;    // 512 cols
    const float invN = 1.0f / (float)MROWS;
    float m = s1[i] * invN;
    float v = q1[i] * invN - m * m;
    float k = g1[i] * rsqrtf(v + 1e-5f);
    sc1[i] = k;
    sh1[i] = be1[i] - m * k;
}

// ---- K5: write Y1 = relu(sc*y + sh) as bf16 (same y expression as k_stat1) --
__global__ __launch_bounds__(256) void k_y1w(const float* __restrict__ Hp,
        const float* __restrict__ rel, const float* __restrict__ V0,
        const float* __restrict__ V1, const float* __restrict__ cvec,
        const float* __restrict__ sc1, const float* __restrict__ sh1,
        unsigned short* __restrict__ Y1) {
    int tid = threadIdx.x;
    int p = blockIdx.x;
    int seg = tid & 63, cg = tid >> 6;
    float4 ha = *(const float4*)(Hp + (size_t)p * 512 + seg * 8);
    float4 hb = *(const float4*)(Hp + (size_t)p * 512 + seg * 8 + 4);
    float4 ca = *(const float4*)(cvec + seg * 8);
    float4 cb = *(const float4*)(cvec + seg * 8 + 4);
    float4 va = *(const float4*)(V0 + seg * 8), vb = *(const float4*)(V0 + seg * 8 + 4);
    float4 wa = *(const float4*)(V1 + seg * 8), wb = *(const float4*)(V1 + seg * 8 + 4);
    float4 sa = *(const float4*)(sc1 + seg * 8), sb = *(const float4*)(sc1 + seg * 8 + 4);
    float4 oa = *(const float4*)(sh1 + seg * 8), ob = *(const float4*)(sh1 + seg * 8 + 4);
    float hc[8] = {ha.x+ca.x, ha.y+ca.y, ha.z+ca.z, ha.w+ca.w,
                   hb.x+cb.x, hb.y+cb.y, hb.z+cb.z, hb.w+cb.w};
    float v0[8] = {va.x,va.y,va.z,va.w,vb.x,vb.y,vb.z,vb.w};
    float v1[8] = {wa.x,wa.y,wa.z,wa.w,wb.x,wb.y,wb.z,wb.w};
    float sc[8] = {sa.x,sa.y,sa.z,sa.w,sb.x,sb.y,sb.z,sb.w};
    float sh[8] = {oa.x,oa.y,oa.z,oa.w,ob.x,ob.y,ob.z,ob.w};
#pragma unroll
    for (int i = 0; i < 4; ++i) {
        int cell = cg + i * 4;
        if (cell < NB) {
            float2 rl = *(const float2*)(rel + (size_t)(p * NB + cell) * 2);
            unsigned short ub[8];
#pragma unroll
            for (int j = 0; j < 8; ++j) {
                float y = fmaf(rl.x, v0[j], fmaf(rl.y, v1[j], hc[j]));
                float z = fmaxf(fmaf(y, sc[j], sh[j]), 0.0f);
                ub[j] = f2bf(z);
            }
            *(uint4*)(Y1 + (size_t)(p * NB + cell) * 512 + seg * 8) = *(uint4*)ub;
        }
    }
}

// ---- GEMM2: 256x256, BK=64, subtile-phase pipeline (R13-verified, ~60 us) ---
template<int K, bool WRITE_C>
__global__ __launch_bounds__(512) void k_gemm256(
        const unsigned short* __restrict__ A, const unsigned short* __restrict__ Bt,
        const float* __restrict__ bias, unsigned short* __restrict__ C,
        int N, float* __restrict__ osum, float* __restrict__ osq,
        unsigned int* __restrict__ mkey) {
    __shared__ __align__(16) unsigned short lds[65536];  // 2 bufs x 32768 elems
    int tid = threadIdx.x;

    int nbt = N >> 8;
    int d = blockIdx.x;
    int m5 = d >> 3;
    int bn = m5 % nbt;
    int bm = (d & 7) + ((m5 / nbt) << 3);
    int row0 = bm << 8, col0 = bn << 8;

    int lane = tid & 63, wave = tid >> 6;
    int wr = wave >> 2, wc = wave & 3;
    int frow = lane & 15, kq = lane >> 4;

    f32x4 zero = {0.f, 0.f, 0.f, 0.f};
    f32x4 acc[8][4];
#pragma unroll
    for (int i = 0; i < 8; ++i)
#pragma unroll
        for (int j = 0; j < 4; ++j) acc[i][j] = zero;

    const unsigned short* gsrc =
        (wave < 4) ? (A  + (size_t)(row0 + (wave << 6) + frow) * K + kq * 8)
                   : (Bt + (size_t)(col0 + ((wave - 4) << 6) + frow) * K + kq * 8);
    unsigned regbase = (wave < 4) ? (unsigned)wave * 2048
                                  : 8192u + (unsigned)(wave - 4) * 2048;

    auto issue2 = [&](int t, int s, int hp) {
        unsigned short* dst = lds + (t & 1) * 32768 + s * 16384 + regbase + hp * 1024;
        const unsigned short* src = gsrc + t * 64 + s * 32 + (size_t)(hp * 32) * K;
        gld_lds16(src,                  dst);
        gld_lds16(src + (size_t)16 * K, dst + 512);
    };

    constexpr int NT = K / 64;
    static_assert(NT >= 2, "need >=2 K-tiles");

    issue2(0, 0, 0); issue2(0, 0, 1); issue2(0, 1, 0); issue2(0, 1, 1);

#pragma unroll
    for (int t = 0; t < NT; ++t) {
        const unsigned short* buf = lds + (t & 1) * 32768;
        bool more = (t + 1 < NT);
#pragma unroll
        for (int s = 0; s < 2; ++s) {
            const unsigned short* sub = buf + s * 16384;
            if (more || s == 0) asm volatile("s_waitcnt vmcnt(4)" ::: "memory");
            else                asm volatile("s_waitcnt vmcnt(0)" ::: "memory");
            __builtin_amdgcn_s_barrier();
            asm volatile("" ::: "memory");
            bf16x8 bfv[4], af[4];
#pragma unroll
            for (int j = 0; j < 4; ++j)
                bfv[j] = *(const bf16x8*)&sub[8192 + (wc * 4 + j) * 512 + kq * 128 + frow * 8];
#pragma unroll
            for (int i = 0; i < 4; ++i)
                af[i] = *(const bf16x8*)&sub[(wr * 8 + i) * 512 + kq * 128 + frow * 8];
            if (more) issue2(t + 1, s, 0);
            __builtin_amdgcn_s_barrier();
            asm volatile("" ::: "memory");
            __builtin_amdgcn_s_setprio(1);
#pragma unroll
            for (int i = 0; i < 4; ++i)
#pragma unroll
                for (int j = 0; j < 4; ++j)
                    acc[i][j] = __builtin_amdgcn_mfma_f32_16x16x32_bf16(af[i], bfv[j], acc[i][j], 0, 0, 0);
            __builtin_amdgcn_s_setprio(0);
#pragma unroll
            for (int i = 0; i < 4; ++i)
                af[i] = *(const bf16x8*)&sub[(wr * 8 + 4 + i) * 512 + kq * 128 + frow * 8];
            if (more) issue2(t + 1, s, 1);
            __builtin_amdgcn_s_barrier();
            asm volatile("" ::: "memory");
            __builtin_amdgcn_s_setprio(1);
#pragma unroll
            for (int i = 0; i < 4; ++i)
#pragma unroll
                for (int j = 0; j < 4; ++j)
                    acc[4 + i][j] = __builtin_amdgcn_mfma_f32_16x16x32_bf16(af[i], bfv[j], acc[4 + i][j], 0, 0, 0);
            __builtin_amdgcn_s_setprio(0);
        }
    }

    float bv[4];
#pragma unroll
    for (int j = 0; j < 4; ++j) bv[j] = bias[col0 + wc * 64 + j * 16 + frow];

#pragma unroll
    for (int j = 0; j < 4; ++j) {
        int col = col0 + wc * 64 + j * 16 + frow;
        float csum = 0.f, csq = 0.f;
#pragma unroll
        for (int i = 0; i < 8; ++i) {
#pragma unroll
            for (int r = 0; r < 4; ++r) {
                float y = acc[i][j][r] + bv[j];
                csum += y; csq = fmaf(y, y, csq);
            }
        }
        csum += __shfl_xor(csum, 16); csum += __shfl_xor(csum, 32);
        csq  += __shfl_xor(csq, 16);  csq  += __shfl_xor(csq, 32);
        if (lane < 16) { atomicAdd(&osum[col], csum); atomicAdd(&osq[col], csq); }
    }

    unsigned short* ldsC = lds;
#pragma unroll
    for (int b = 0; b < 4; ++b) {
        __syncthreads();
        if (wr == (b >> 1)) {
#pragma unroll
            for (int j = 0; j < 4; ++j) {
#pragma unroll
                for (int ii = 0; ii < 4; ++ii) {
                    int i = (b & 1) * 4 + ii;
#pragma unroll
                    for (int r = 0; r < 4; ++r) {
                        float y = acc[i][j][r] + bv[j];
                        ldsC[(ii * 16 + kq * 4 + r) * 264 + wc * 64 + j * 16 + frow] = f2bf(y);
                    }
                }
            }
        }
        __syncthreads();
        if (WRITE_C) {
#pragma unroll
            for (int it = 0; it < 4; ++it) {
                int s = it * 512 + tid;
                int brow = s >> 5, seg = s & 31;
                *(uint4*)(C + (size_t)(row0 + b * 64 + brow) * N + col0 + seg * 8) =
                    *(const uint4*)&ldsC[brow * 264 + seg * 8];
            }
        } else {
            int col = tid & 255, half = tid >> 8;
            int lrow0 = half * 32;
            int grow = row0 + b * 64 + lrow0;
            int curp = grow / 15;
            int rem = 15 - (grow - curp * 15);
            float mx = -3.0e38f;
#pragma unroll
            for (int r = 0; r < 32; ++r) {
                mx = fmaxf(mx, bf2f(ldsC[(lrow0 + r) * 264 + col]));
                if (--rem == 0) {
                    atomicMax(&mkey[(size_t)curp * 1024 + col0 + col], fkey(mx));
                    mx = -3.0e38f; ++curp; rem = 15;
                }
            }
            if (rem != 15)
                atomicMax(&mkey[(size_t)curp * 1024 + col0 + col], fkey(mx));
        }
    }
}

// ---- finalize: out = relu(sc2 * max_y + sh2) from u32-keyed maxima ----------
__global__ void k_bnfin(const unsigned int* __restrict__ mkey, const float* __restrict__ s2,
                        const float* __restrict__ q2, const float* __restrict__ g2,
                        const float* __restrict__ be2, float* __restrict__ out) {
    int idx = blockIdx.x * 256 + threadIdx.x;
    int p = idx >> 7, cb = idx & 127;
    int c0 = cb << 3;
    const float invN = 1.0f / (float)MROWS;
    float4 sa = *(const float4*)(s2 + c0),  sb = *(const float4*)(s2 + c0 + 4);
    float4 qa = *(const float4*)(q2 + c0),  qb = *(const float4*)(q2 + c0 + 4);
    float4 ga = *(const float4*)(g2 + c0),  gb = *(const float4*)(g2 + c0 + 4);
    float4 ea = *(const float4*)(be2 + c0), eb = *(const float4*)(be2 + c0 + 4);
    float sv[8] = {sa.x,sa.y,sa.z,sa.w,sb.x,sb.y,sb.z,sb.w};
    float qv[8] = {qa.x,qa.y,qa.z,qa.w,qb.x,qb.y,qb.z,qb.w};
    float gv[8] = {ga.x,ga.y,ga.z,ga.w,gb.x,gb.y,gb.z,gb.w};
    float ev[8] = {ea.x,ea.y,ea.z,ea.w,eb.x,eb.y,eb.z,eb.w};
    uint4 k0 = *(const uint4*)(mkey + (size_t)p * 1024 + c0);
    uint4 k1 = *(const uint4*)(mkey + (size_t)p * 1024 + c0 + 4);
    unsigned kv[8] = {k0.x,k0.y,k0.z,k0.w,k1.x,k1.y,k1.z,k1.w};
    float o[8];
#pragma unroll
    for (int j = 0; j < 8; ++j) {
        float m = sv[j] * invN;
        float v = qv[j] * invN - m * m;
        float k = gv[j] * rsqrtf(v + 1e-5f);
        float sh = ev[j] - m * k;
        o[j] = fmaxf(fmaf(funkey(kv[j]), k, sh), 0.0f);
    }
    float4 o0 = {o[0], o[1], o[2], o[3]};
    float4 o1 = {o[4], o[5], o[6], o[7]};
    *(float4*)(out + (size_t)p * 1024 + c0)     = o0;
    *(float4*)(out + (size_t)p * 1024 + c0 + 4) = o1;
}

extern "C" void kernel_launch(void* const* d_in, const int* in_sizes, int n_in,
                              void* d_out, int out_size, void* d_ws, size_t ws_size,
                              hipStream_t stream) {
    const float* h       = (const float*)d_in[0];
    const float* end_pos = (const float*)d_in[1];
    const float* rel_pos = (const float*)d_in[2];
    const float* bpts    = (const float*)d_in[3];
    const float* Wsp     = (const float*)d_in[4];
    const float* bsp     = (const float*)d_in[5];
    const float* W1      = (const float*)d_in[6];
    const float* b1      = (const float*)d_in[7];
    const float* g1      = (const float*)d_in[8];
    const float* be1     = (const float*)d_in[9];
    const float* W2      = (const float*)d_in[10];
    const float* b2      = (const float*)d_in[11];
    const float* g2      = (const float*)d_in[12];
    const float* be2     = (const float*)d_in[13];
    float* out = (float*)d_out;

    // ws: [stats 12288][mkey 8388608][pkeys 1228800][w1t 131072][w2t 1048576]
    //     [hbf 262144][V0/V1/c/sc1/sh1 10240][H' 4194304][rel 245760][Y1 31457280]
    char* ws = (char*)d_ws;
    float* s1  = (float*)ws;
    float* q1  = s1 + 512;
    float* s2  = q1 + 512;
    float* q2  = s2 + 1024;
    unsigned int* mkey        = (unsigned int*)(ws + 12288);
    unsigned long long* pkeys = (unsigned long long*)(ws + 12288 + 8388608);
    unsigned short* w1t = (unsigned short*)(ws + 9629696);
    unsigned short* w2t = (unsigned short*)(ws + 9760768);
    unsigned short* hbf = (unsigned short*)(ws + 10809344);
    float* V0   = (float*)(ws + 11071488);
    float* V1   = V0 + 512;
    float* cvec = V1 + 512;
    float* sc1  = cvec + 512;
    float* sh1  = sc1 + 512;
    float* Hp   = (float*)(ws + 11081728);
    float* rel  = (float*)(ws + 15276032);
    unsigned short* Y1 = (unsigned short*)(ws + 15521792);

    k_front<<<12566, 256, 0, stream>>>(W1, W2, w1t, w2t, s1, end_pos, rel_pos,
                                       bpts, pkeys, h, hbf, Wsp, bsp, b1, V0, V1, cvec);
    k_assemble<<<P_N, 64, 0, stream>>>(pkeys, end_pos, rel_pos, bpts, rel);
    k_hgemm<<<32, 512, 0, stream>>>(hbf, w1t, Hp);
    k_stat1<<<P_N / 4, 256, 0, stream>>>(Hp, rel, V0, V1, cvec, s1, q1);
    k_coef1<<<2, 256, 0, stream>>>(s1, q1, g1, be1, sc1, sh1);
    k_y1w<<<P_N, 256, 0, stream>>>(Hp, rel, V0, V1, cvec, sc1, sh1, Y1);
    k_gemm256<512, false><<<(MROWS / 256) * (1024 / 256), 512, 0, stream>>>(
        Y1, w2t, b2, nullptr, 1024, s2, q2, mkey);
    k_bnfin<<<(P_N * 128) / 256, 256, 0, stream>>>(mkey, s2, q2, g2, be2, out);
}